// Round 10
// baseline (1666.402 us; speedup 1.0000x reference)
//
#include <hip/hip_runtime.h>

typedef unsigned short ushortT;
typedef unsigned int uintT;
typedef unsigned long long u64T;
typedef __bf16 bf16x8 __attribute__((ext_vector_type(8)));
typedef float f32x4 __attribute__((ext_vector_type(4)));

#define B_ 16
#define N_ 8192
#define G_ 512
#define KNN_ 32
#define M_ (B_*G_)      // 8192 groups
#define R_ (M_*KNN_)    // 262144 rows

static __device__ __forceinline__ ushortT f2bf(float f){
  uintT u = __float_as_uint(f);
  return (ushortT)((u + 0x7fffu + ((u >> 16) & 1u)) >> 16);
}
static __device__ __forceinline__ float bf2f(ushortT h){ return __uint_as_float(((uintT)h) << 16); }

union U16 { uint4 u; ushortT s[8]; bf16x8 v; };

// packed fp32 (VOP3P). RNE rounding identical to __fadd_rn/__fmul_rn per half.
static __device__ __forceinline__ float2 pk_add(float2 a, float2 b){
  float2 d;
  asm("v_pk_add_f32 %0, %1, %2" : "=v"(d) : "v"(a), "v"(b));
  return d;
}
static __device__ __forceinline__ float2 pk_mul(float2 a, float2 b){
  float2 d;
  asm("v_pk_mul_f32 %0, %1, %2" : "=v"(d) : "v"(a), "v"(b));
  return d;
}

// u64 max with butterfly partner via ds_swizzle (masks 1..16, within 32-lane halves)
#define SWZ_MAX(vv, pat) {                                              \
    uintT lo_ = (uintT)(vv), hi_ = (uintT)((vv) >> 32);                 \
    uintT olo_ = (uintT)__builtin_amdgcn_ds_swizzle((int)lo_, (pat));   \
    uintT ohi_ = (uintT)__builtin_amdgcn_ds_swizzle((int)hi_, (pat));   \
    u64T o_ = ((u64T)ohi_ << 32) | olo_;                                \
    (vv) = (o_ > (vv)) ? o_ : (vv); }

// f32 max with butterfly partner via ds_swizzle
#define SWZF_MAX(vv, pat) {                                                          \
    float o_ = __uint_as_float((uintT)__builtin_amdgcn_ds_swizzle(                   \
        (int)__float_as_uint(vv), (pat)));                                           \
    (vv) = fmaxf((vv), o_); }

// u32 max with butterfly partner via ds_swizzle
#define SWZU_MAX(vv, pat) {                                                          \
    uintT o_ = (uintT)__builtin_amdgcn_ds_swizzle((int)(vv), (pat));                 \
    (vv) = ((o_ > (vv)) ? o_ : (vv)); }

// ---------------- FPS: exact fp32 replication, 1 block/batch, 512 thr, pk-f32 update --------
// Selection bit-identical to round-9 kernel: p+(-c) == __fsub_rn(p,c); pk mul/add are RNE;
// same association ((dx2+dy2)+dz2); wave winner = (max dist, lowest p); cross-wave via u64
// (distbits<<32)|~p max (unchanged from r9).
__global__ __launch_bounds__(512) void fps_kernel(const float* __restrict__ xyz,
                                                  float* __restrict__ center){
  const int b = blockIdx.x;
  const int tid = threadIdx.x;                   // 512 threads = 8 waves
  const float* P = xyz + (size_t)b * N_ * 3;
  __shared__ float sx[N_], sy[N_], sz[N_];       // 96 KB
  __shared__ u64T slot[2][8];
  float2 px[8], py[8], pz[8], dist[8];           // halves = chunks 2k (lo), 2k+1 (hi)
  uintT nI[16];
#pragma unroll
  for (int k = 0; k < 8; k++){
    int p0 = tid + ((2*k    ) << 9);
    int p1 = tid + ((2*k + 1) << 9);
    float x0 = P[p0*3+0], y0 = P[p0*3+1], z0 = P[p0*3+2];
    float x1 = P[p1*3+0], y1 = P[p1*3+1], z1 = P[p1*3+2];
    sx[p0] = x0; sy[p0] = y0; sz[p0] = z0;
    sx[p1] = x1; sy[p1] = y1; sz[p1] = z1;
    px[k] = make_float2(x0, x1);
    py[k] = make_float2(y0, y1);
    pz[k] = make_float2(z0, z1);
    dist[k] = make_float2(1e10f, 1e10f);
    nI[2*k    ] = ~(uintT)p0;
    nI[2*k + 1] = ~(uintT)p1;
  }
  __syncthreads();
  const int lane = tid & 63, wv = tid >> 6;
  int far = 0;
  for (int s = 0; s < G_; s++){
    const float cx = sx[far], cy = sy[far], cz = sz[far];
    if (tid == 0){
      float* co = center + ((size_t)b * G_ + s) * 3;
      co[0] = cx; co[1] = cy; co[2] = cz;
    }
    const float2 ncx = make_float2(-cx, -cx);
    const float2 ncy = make_float2(-cy, -cy);
    const float2 ncz = make_float2(-cz, -cz);
#pragma unroll
    for (int k = 0; k < 8; k++){
      float2 dx = pk_add(px[k], ncx);
      float2 dy = pk_add(py[k], ncy);
      float2 dz = pk_add(pz[k], ncz);
      float2 d  = pk_add(pk_add(pk_mul(dx, dx), pk_mul(dy, dy)), pk_mul(dz, dz));
      dist[k] = make_float2(fminf(dist[k].x, d.x), fminf(dist[k].y, d.y));
    }
    // in-lane value max (tree; compiler may fuse to v_max3)
    float m0 = fmaxf(fmaxf(dist[0].x, dist[0].y), fmaxf(dist[1].x, dist[1].y));
    float m1 = fmaxf(fmaxf(dist[2].x, dist[2].y), fmaxf(dist[3].x, dist[3].y));
    float m2 = fmaxf(fmaxf(dist[4].x, dist[4].y), fmaxf(dist[5].x, dist[5].y));
    float m3 = fmaxf(fmaxf(dist[6].x, dist[6].y), fmaxf(dist[7].x, dist[7].y));
    float bv = fmaxf(fmaxf(m0, m1), fmaxf(m2, m3));
    // wave-wide value butterfly
    SWZF_MAX(bv, 0x041F)
    SWZF_MAX(bv, 0x081F)
    SWZF_MAX(bv, 0x101F)
    SWZF_MAX(bv, 0x201F)
    SWZF_MAX(bv, 0x401F)
    { float o = __shfl_xor(bv, 32); bv = fmaxf(bv, o); }
    // in-lane index candidate: lowest p with dist==bv  (max ~p; 0 if no match)
    uintT cand = 0;
#pragma unroll
    for (int k = 0; k < 8; k++){
      uintT c0 = (dist[k].x == bv) ? nI[2*k]     : 0u;
      uintT c1 = (dist[k].y == bv) ? nI[2*k + 1] : 0u;
      uintT cm = (c0 > c1) ? c0 : c1;
      cand = (cm > cand) ? cm : cand;
    }
    // wave-wide index butterfly (some lane in this wave matches bv)
    SWZU_MAX(cand, 0x041F)
    SWZU_MAX(cand, 0x081F)
    SWZU_MAX(cand, 0x101F)
    SWZU_MAX(cand, 0x201F)
    SWZU_MAX(cand, 0x401F)
    { uintT o = __shfl_xor(cand, 32); cand = (o > cand) ? o : cand; }
    u64T best = ((u64T)__float_as_uint(bv) << 32) | cand;
    if (lane == 0) slot[s & 1][wv] = best;
    __syncthreads();
    u64T v = slot[s & 1][lane & 7];
    SWZ_MAX(v, 0x041F)
    SWZ_MAX(v, 0x081F)
    SWZ_MAX(v, 0x101F)
    far = (int)(~(uintT)v) & (N_ - 1);
  }
}

// ---------------- kNN: per-wave barrier-free extraction + single merge (round-4) ------------
__global__ __launch_bounds__(256) void knn_kernel(const float* __restrict__ xyz,
                                                  const float* __restrict__ center,
                                                  int* __restrict__ knnIdx){
  const int mc = blockIdx.x;
  const int b  = mc >> 9;
  const int tid = threadIdx.x;
  const int lane = tid & 63, w = tid >> 6;
  const float* P = xyz + (size_t)b * N_ * 3;
  const float cx = center[mc*3+0], cy = center[mc*3+1], cz = center[mc*3+2];
  const float tc = __fadd_rn(__fadd_rn(__fmul_rn(cx,cx), __fmul_rn(cy,cy)), __fmul_rn(cz,cz));
  uintT key[32];
  uintT bd = 0xFFFFFFFFu; int bk = 0;
#pragma unroll
  for (int k = 0; k < 32; k++){
    int p = tid + (k << 8);
    float x = P[p*3+0], y = P[p*3+1], z = P[p*3+2];
    float tx  = __fadd_rn(__fadd_rn(__fmul_rn(x,x), __fmul_rn(y,y)), __fmul_rn(z,z));
    float dot = __fadd_rn(__fadd_rn(__fmul_rn(cx,x), __fmul_rn(cy,y)), __fmul_rn(cz,z));
    float d   = __fsub_rn(__fadd_rn(tc, tx), __fmul_rn(2.0f, dot));
    uintT bb  = __float_as_uint(d);
    uintT kk  = bb ^ ((uintT)((int)bb >> 31) | 0x80000000u);   // monotone map
    key[k] = kk;
    if (kk < bd){ bd = kk; bk = k; }
  }
  __shared__ u64T sKeys[128];
  for (int r = 0; r < KNN_; r++){
    u64T me = ((u64T)bd << 32) | (uintT)(tid + (bk << 8));
    u64T m = me;
#pragma unroll
    for (int msk = 32; msk >= 1; msk >>= 1){
      u64T o = __shfl_xor(m, msk);
      m = (o < m) ? o : m;
    }
    if (lane == 0) sKeys[w * 32 + r] = m;
    if (me == m){
      uintT nb = 0xFFFFFFFFu; int nk = 0;
#pragma unroll
      for (int k = 0; k < 32; k++){
        uintT vv = (k == bk) ? 0xFFFFFFFFu : key[k];
        key[k] = vv;
        if (vv < nb){ nb = vv; nk = k; }
      }
      bd = nb; bk = nk;
    }
  }
  __syncthreads();
  if (w == 0){
    u64T e0 = sKeys[lane], e1 = sKeys[lane + 64];
    for (int r = 0; r < KNN_; r++){
      u64T be = (e0 < e1) ? e0 : e1;
      u64T m = be;
#pragma unroll
      for (int msk = 32; msk >= 1; msk >>= 1){
        u64T o = __shfl_xor(m, msk);
        m = (o < m) ? o : m;
      }
      if (lane == 0) knnIdx[(size_t)mc * KNN_ + r] = (int)(uintT)m;
      if (be == m){
        if (e0 == m) e0 = ~0ull; else e1 = ~0ull;
      }
    }
  }
}

// ---------------- moments + prep1: BN1 analytic stats ----------------
__global__ __launch_bounds__(256) void moments_kernel(const float* __restrict__ xyz,
                                                      const int* __restrict__ knnIdx,
                                                      float* __restrict__ Mpart){
  const int t = threadIdx.x, blk = blockIdx.x;
  float m[9];
#pragma unroll
  for (int k = 0; k < 9; k++) m[k] = 0.f;
  for (int i = 0; i < 4; i++){
    int row = blk * 1024 + i * 256 + t;
    int p = knnIdx[row];
    int b = row >> 14;
    const float* pt = xyz + ((size_t)(b * N_ + p)) * 3;
    float x = pt[0], y = pt[1], z = pt[2];
    m[0]+=x; m[1]+=y; m[2]+=z; m[3]+=x*x; m[4]+=y*y; m[5]+=z*z; m[6]+=x*y; m[7]+=x*z; m[8]+=y*z;
  }
  __shared__ float red[4][9];
  const int lane = t & 63, w = t >> 6;
#pragma unroll
  for (int k = 0; k < 9; k++){
    float v = m[k];
#pragma unroll
    for (int sh = 32; sh >= 1; sh >>= 1) v += __shfl_xor(v, sh);
    if (lane == 0) red[w][k] = v;
  }
  __syncthreads();
  if (t < 9) Mpart[blk * 9 + t] = red[0][t] + red[1][t] + red[2][t] + red[3][t];
}

__global__ __launch_bounds__(128) void prep1_kernel(const float* __restrict__ Mpart,
                                                    const float* __restrict__ W1,
                                                    const float* __restrict__ b1,
                                                    const float* __restrict__ g1,
                                                    const float* __restrict__ be1,
                                                    float4* __restrict__ F1c){
  __shared__ float S[9];
  const int t = threadIdx.x;
  if (t < 9){
    float s = 0.f;
    for (int i = 0; i < 256; i++) s += Mpart[i * 9 + t];
    S[t] = s;
  }
  __syncthreads();
  const float invN = 1.0f / (float)R_;
  float mx = S[0]*invN, my = S[1]*invN, mz = S[2]*invN;
  float Cxx = S[3]*invN - mx*mx, Cyy = S[4]*invN - my*my, Czz = S[5]*invN - mz*mz;
  float Cxy = S[6]*invN - mx*my, Cxz = S[7]*invN - mx*mz, Cyz = S[8]*invN - my*mz;
  const int ch = t;
  float w0 = W1[ch*3+0], w1 = W1[ch*3+1], w2 = W1[ch*3+2], bb = b1[ch];
  float var = w0*w0*Cxx + w1*w1*Cyy + w2*w2*Czz + 2.f*(w0*w1*Cxy + w0*w2*Cxz + w1*w2*Cyz);
  float mu  = w0*mx + w1*my + w2*mz + bb;
  float sc  = rsqrtf(var + 1e-5f) * g1[ch];
  float sh  = be1[ch] - mu * sc;
  F1c[ch] = make_float4(w0*sc, w1*sc, w2*sc, fmaf(bb, sc, sh));
}

__global__ __launch_bounds__(256) void cast3_kernel(const float* __restrict__ W2,
                                                    const float* __restrict__ W3,
                                                    const float* __restrict__ W4,
                                                    ushortT* W2b, ushortT* W3b, ushortT* W4b){
  int i = blockIdx.x * 256 + threadIdx.x;
  if (i < 32768)  W2b[i] = f2bf(W2[i]);
  if (i < 262144) W3b[i] = f2bf(W3[i]);
  if (i < 65536)  W4b[i] = f2bf(W4[i]);
}

// ---------------- per-lane layer-1 A fragments (no LDS): 4 x bf16x8 ----------------
static __device__ __forceinline__ void a1_frags(const float* __restrict__ xyz,
                                                const int* __restrict__ knnIdx,
                                                const float4* __restrict__ F1c,
                                                int row, int lg, bf16x8 fr[4]){
  const int p = knnIdx[row];
  const int b = row >> 14;
  const float* pt = xyz + ((size_t)(b * N_ + p)) * 3;
  const float x = pt[0], y = pt[1], z = pt[2];
#pragma unroll
  for (int s = 0; s < 4; s++){
    U16 u;
#pragma unroll
    for (int j = 0; j < 8; j++){
      const float4 f = F1c[s * 32 + lg * 8 + j];
      const float h = fmaxf(fmaf(x, f.x, fmaf(y, f.y, fmaf(z, f.z, f.w))), 0.f);
      u.s[j] = f2bf(h);
    }
    fr[s] = u.v;
  }
}

// ---------------- f2g (FALLBACK): per-64-row tile, fg only ----------------
__global__ __launch_bounds__(256) void f2g_kernel(const float* __restrict__ xyz,
                                                  const int* __restrict__ knnIdx,
                                                  const float4* __restrict__ F1c,
                                                  const ushortT* __restrict__ W2bf,
                                                  const float* __restrict__ b2,
                                                  ushortT* __restrict__ fg){
  const int rc = blockIdx.x;
  const int t = threadIdx.x, lane = t & 63, w = t >> 6;
  const int lr = lane & 15, lg = lane >> 4;
  const int row = rc * 64 + w * 16 + lr;
  bf16x8 a1[4];
  a1_frags(xyz, knnIdx, F1c, row, lg, a1);
  f32x4 acc[16];
#pragma unroll
  for (int c = 0; c < 16; c++) acc[c] = (f32x4){0.f,0.f,0.f,0.f};
#pragma unroll
  for (int s = 0; s < 4; s++)
#pragma unroll
    for (int ct = 0; ct < 16; ct++){
      bf16x8 bb = *reinterpret_cast<const bf16x8*>(W2bf + (size_t)(ct*16+lr)*128 + s*32 + lg*8);
      acc[ct] = __builtin_amdgcn_mfma_f32_16x16x32_bf16(a1[s], bb, acc[ct], 0, 0, 0);
    }
  __shared__ float wmax[4][256];
#pragma unroll
  for (int ct = 0; ct < 16; ct++){
    float cmax = fmaxf(fmaxf(acc[ct][0], acc[ct][1]), fmaxf(acc[ct][2], acc[ct][3]));
    cmax = fmaxf(cmax, __shfl_xor(cmax, 16));
    cmax = fmaxf(cmax, __shfl_xor(cmax, 32));
    if (lg == 0) wmax[w][ct*16+lr] = cmax;
  }
  __syncthreads();
  {
    float bb = b2[t];
    fg[((size_t)rc*2 + 0)*256 + t] = f2bf(fmaxf(wmax[0][t], wmax[1][t]) + bb);
    fg[((size_t)rc*2 + 1)*256 + t] = f2bf(fmaxf(wmax[2][t], wmax[3][t]) + bb);
  }
}

// ---------------- enc2s (S2 PATH): phaseA + fg + fgsum + S2 -> global (swizzled layout) -----
__global__ __launch_bounds__(512) void enc2s_kernel(const float* __restrict__ xyz,
                                                    const int* __restrict__ knnIdx,
                                                    const float4* __restrict__ F1c,
                                                    const ushortT* __restrict__ W2bf,
                                                    const float* __restrict__ b2,
                                                    ushortT* __restrict__ fg,
                                                    float* __restrict__ fgsum,
                                                    ushortT* __restrict__ S2g){
  __shared__ ushortT sS2[128 * 256];           // 64 KB
  __shared__ float wmax[8][256];               // 8 KB
  __shared__ float wsum[8][256];               // 8 KB
  const int blk = blockIdx.x;                  // 2048 tiles of 128 rows = 4 groups
  const int t = threadIdx.x, lane = t & 63, wv = t >> 6;
  const int lr = lane & 15, lg = lane >> 4;
  bf16x8 a1[4];
  a1_frags(xyz, knnIdx, F1c, blk*128 + wv*16 + lr, lg, a1);
  f32x4 acc[16];
#pragma unroll
  for (int c = 0; c < 16; c++) acc[c] = (f32x4){0.f,0.f,0.f,0.f};
#pragma unroll
  for (int s = 0; s < 4; s++)
#pragma unroll
    for (int ct = 0; ct < 16; ct++){
      bf16x8 bb = *reinterpret_cast<const bf16x8*>(W2bf + (size_t)(ct*16+lr)*128 + s*32 + lg*8);
      acc[ct] = __builtin_amdgcn_mfma_f32_16x16x32_bf16(a1[s], bb, acc[ct], 0, 0, 0);
    }
#pragma unroll
  for (int ct = 0; ct < 16; ct++){
    const int col = ct*16 + lr;
    const float bb = b2[col];
    float cmax = -3.0e38f, csum = 0.f;
#pragma unroll
    for (int i = 0; i < 4; i++){
      int row = wv*16 + lg*4 + i;
      ushortT sv = f2bf(acc[ct][i] + bb);
      sS2[row*256 + (col ^ ((row & 7) << 3))] = sv;
      csum += bf2f(sv);
      cmax = fmaxf(cmax, acc[ct][i]);          // raw acc; bias added at emission (r4 semantics)
    }
    cmax = fmaxf(cmax, __shfl_xor(cmax, 16));
    cmax = fmaxf(cmax, __shfl_xor(cmax, 32));
    csum += __shfl_xor(csum, 16); csum += __shfl_xor(csum, 32);
    if (lg == 0){ wmax[wv][col] = cmax; wsum[wv][col] = csum; }
  }
  __syncthreads();
#pragma unroll
  for (int q = 0; q < 2; q++){
    int gl = q*2 + (t >> 8);                   // 0..3
    int col = t & 255;
    float bb = b2[col];
    fg   [((size_t)blk*4 + gl)*256 + col] = f2bf(fmaxf(wmax[2*gl][col], wmax[2*gl+1][col]) + bb);
    fgsum[((size_t)blk*4 + gl)*256 + col] = wsum[2*gl][col] + wsum[2*gl+1][col];
  }
  // copy S2 tile out (linear copy preserves swizzled layout)
  const uint4* src = reinterpret_cast<const uint4*>(sS2);
  uint4* dst = reinterpret_cast<uint4*>(S2g + (size_t)blk * 32768);
#pragma unroll
  for (int i = 0; i < 8; i++) dst[t + i*512] = src[t + i*512];
}

// ---------------- u: U = fg @ W3a^T + b3 (8192 x 512, K=256) ----------------
__global__ __launch_bounds__(256) void u_kernel(const ushortT* __restrict__ fg,
                                                const ushortT* __restrict__ W3bf,
                                                const float* __restrict__ b3,
                                                float* __restrict__ U){
  const int bid = blockIdx.x;
  const int rc = bid >> 2, cc = bid & 3;
  const int t = threadIdx.x, lane = t & 63, w = t >> 6;
  const int lr = lane & 15, lg = lane >> 4;
  const int arow = rc * 64 + w * 16 + lr;
  f32x4 acc[8];
#pragma unroll
  for (int c = 0; c < 8; c++) acc[c] = (f32x4){0.f,0.f,0.f,0.f};
#pragma unroll
  for (int s = 0; s < 8; s++){
    bf16x8 a = *reinterpret_cast<const bf16x8*>(fg + (size_t)arow*256 + s*32 + lg*8);
#pragma unroll
    for (int ct = 0; ct < 8; ct++){
      bf16x8 bb = *reinterpret_cast<const bf16x8*>(W3bf + (size_t)(cc*128+ct*16+lr)*512 + s*32 + lg*8);
      acc[ct] = __builtin_amdgcn_mfma_f32_16x16x32_bf16(a, bb, acc[ct], 0, 0, 0);
    }
  }
#pragma unroll
  for (int ct = 0; ct < 8; ct++){
    int col = cc*128 + ct*16 + lr;
    float bb = b3[col];
#pragma unroll
    for (int i = 0; i < 4; i++){
      int crow = rc*64 + w*16 + lg*4 + i;
      U[(size_t)crow * 512 + col] = acc[ct][i] + bb;
    }
  }
}

// ---------------- v: V = bf16(fgsum) @ W3b^T; per-block UV partials (r5-verified) ----------
__global__ __launch_bounds__(256) void v_kernel(const float* __restrict__ fgsum,
                                                const ushortT* __restrict__ W3bf,
                                                const float* __restrict__ U,
                                                float* __restrict__ UVpart){
  const int bid = blockIdx.x;
  const int rc = bid >> 2, cc = bid & 3;
  const int t = threadIdx.x, lane = t & 63, w = t >> 6;
  const int lr = lane & 15, lg = lane >> 4;
  const int arow = rc * 64 + w * 16 + lr;
  f32x4 acc[8];
#pragma unroll
  for (int c = 0; c < 8; c++) acc[c] = (f32x4){0.f,0.f,0.f,0.f};
#pragma unroll
  for (int s = 0; s < 8; s++){
    int kk = s*32 + lg*8;
    float4 fa = *reinterpret_cast<const float4*>(&fgsum[(size_t)arow*256 + kk]);
    float4 fb = *reinterpret_cast<const float4*>(&fgsum[(size_t)arow*256 + kk + 4]);
    U16 ua;
    ua.s[0]=f2bf(fa.x); ua.s[1]=f2bf(fa.y); ua.s[2]=f2bf(fa.z); ua.s[3]=f2bf(fa.w);
    ua.s[4]=f2bf(fb.x); ua.s[5]=f2bf(fb.y); ua.s[6]=f2bf(fb.z); ua.s[7]=f2bf(fb.w);
#pragma unroll
    for (int ct = 0; ct < 8; ct++){
      bf16x8 bb = *reinterpret_cast<const bf16x8*>(W3bf + (size_t)(cc*128+ct*16+lr)*512 + 256 + kk);
      acc[ct] = __builtin_amdgcn_mfma_f32_16x16x32_bf16(ua.v, bb, acc[ct], 0, 0, 0);
    }
  }
  __shared__ float sUV[4][128];
#pragma unroll
  for (int ct = 0; ct < 8; ct++){
    int col = cc*128 + ct*16 + lr;
    float uv = 0.f;
#pragma unroll
    for (int i = 0; i < 4; i++){
      int g = rc*64 + w*16 + lg*4 + i;
      uv += acc[ct][i] * U[(size_t)g * 512 + col];
    }
    uv += __shfl_xor(uv, 16); uv += __shfl_xor(uv, 32);
    if (lg == 0) sUV[w][ct*16+lr] = uv;
  }
  __syncthreads();
  if (t < 128)
    UVpart[(size_t)rc * 512 + cc*128 + t] = sUV[0][t] + sUV[1][t] + sUV[2][t] + sUV[3][t];
}

// ---------------- gram2 (S2 PATH): G partials from materialized S2 (no phaseA, no spill) ----
__global__ __launch_bounds__(512) void gram2_kernel(const ushortT* __restrict__ S2g,
                                                    float* __restrict__ Gpart,
                                                    int tilesPerBlk){
  __shared__ ushortT sT[256 * 136];            // 69.6 KB transposed [col][row], +8 pad
  const int blk = blockIdx.x;
  const int t = threadIdx.x, lane = t & 63, wv = t >> 6;
  const int lr = lane & 15, lg = lane >> 4;
  f32x4 gacc[32];
#pragma unroll
  for (int c = 0; c < 32; c++) gacc[c] = (f32x4){0.f,0.f,0.f,0.f};
  const int r  = t >> 2;
  const int cb = (t & 3) * 64;
  for (int tile = 0; tile < tilesPerBlk; tile++){
    const int rt = blk * tilesPerBlk + tile;
    __syncthreads();                           // prev tile's MFMA reads complete
    const int swz = (r & 7) << 3;
#pragma unroll
    for (int u4 = 0; u4 < 8; u4++){
      int sc0 = cb + u4*8;                     // stored (swizzled) col index, 8-aligned
      U16 raw; raw.u = *reinterpret_cast<const uint4*>(S2g + (size_t)rt*32768 + r*256 + sc0);
      int tc0 = sc0 ^ swz;                     // true col (8-block preserved)
#pragma unroll
      for (int j = 0; j < 8; j++)
        sT[(tc0 + j)*136 + r] = raw.s[j];
    }
    __syncthreads();
#pragma unroll
    for (int ks = 0; ks < 4; ks++){
      const int k0 = ks*32 + lg*8;
      bf16x8 aA[2];
#pragma unroll
      for (int ii = 0; ii < 2; ii++)
        aA[ii] = *reinterpret_cast<const bf16x8*>(&sT[((2*wv+ii)*16 + lr)*136 + k0]);
#pragma unroll
      for (int j = 0; j < 16; j++){
        bf16x8 bB = *reinterpret_cast<const bf16x8*>(&sT[(j*16 + lr)*136 + k0]);
        gacc[0*16+j] = __builtin_amdgcn_mfma_f32_16x16x32_bf16(aA[0], bB, gacc[0*16+j], 0,0,0);
        gacc[1*16+j] = __builtin_amdgcn_mfma_f32_16x16x32_bf16(aA[1], bB, gacc[1*16+j], 0,0,0);
      }
    }
  }
  float* Gp = Gpart + (size_t)blk * 65536;
#pragma unroll
  for (int ii = 0; ii < 2; ii++)
#pragma unroll
    for (int j = 0; j < 16; j++)
#pragma unroll
      for (int i = 0; i < 4; i++){
        int ci = (2*wv + ii)*16 + lg*4 + i;
        int cj = j*16 + lr;
        Gp[ci*256 + cj] = gacc[ii*16+j][i];
      }
}

// ---------------- gred: reduce Gpart -> G (r5-verified) ----------------
__global__ __launch_bounds__(256) void gred_kernel(const float* __restrict__ Gpart,
                                                   float* __restrict__ G, int nPart){
  int i = blockIdx.x * 256 + threadIdx.x;
  float s = 0.f;
  for (int b = 0; b < nPart; b++) s += Gpart[(size_t)b * 65536 + i];
  G[i] = s;
}

// ---------------- ured: per-channel sums of U, U^2, colsum fgsum (r5-verified) --------------
__global__ __launch_bounds__(256) void ured_kernel(const float* __restrict__ U,
                                                   const float* __restrict__ fgsum,
                                                   float* __restrict__ Upart,
                                                   float* __restrict__ Usqpart,
                                                   float* __restrict__ CSpart){
  const int blk = blockIdx.x;
  const int slice = blk >> 3, part = blk & 7;
  const int t = threadIdx.x;
  {
    const int cl = t & 63, gsub = t >> 6;
    const int c = part*64 + cl;
    float su = 0.f, sq = 0.f;
    for (int g = slice*1024 + gsub; g < slice*1024 + 1024; g += 4){
      float u = U[(size_t)g * 512 + c];
      su += u; sq += u*u;
    }
    __shared__ float rU[4][64], rQ[4][64];
    rU[gsub][cl] = su; rQ[gsub][cl] = sq;
    __syncthreads();
    if (t < 64){
      Upart  [(size_t)slice*512 + part*64 + t] = rU[0][t]+rU[1][t]+rU[2][t]+rU[3][t];
      Usqpart[(size_t)slice*512 + part*64 + t] = rQ[0][t]+rQ[1][t]+rQ[2][t]+rQ[3][t];
    }
  }
  __syncthreads();
  {
    const int cl = t & 31, gsub = t >> 5;
    const int c2 = part*32 + cl;
    float cs = 0.f;
    for (int g = slice*1024 + gsub; g < slice*1024 + 1024; g += 8)
      cs += fgsum[(size_t)g * 256 + c2];
    __shared__ float rC[8][32];
    rC[gsub][cl] = cs;
    __syncthreads();
    if (t < 32){
      float s = 0.f;
#pragma unroll
      for (int k = 0; k < 8; k++) s += rC[k][t];
      CSpart[(size_t)slice*256 + part*32 + t] = s;
    }
  }
}

// ---------------- fin2: assemble BN2 scale/shift from moments (r5-verified) ----------------
__global__ __launch_bounds__(256) void fin2_kernel(const float* __restrict__ G,
                                                   const float* __restrict__ CSpart,
                                                   const float* __restrict__ Upart,
                                                   const float* __restrict__ Usqpart,
                                                   const float* __restrict__ UVpart,
                                                   const ushortT* __restrict__ W3bf,
                                                   const float* __restrict__ g2,
                                                   const float* __restrict__ be2,
                                                   float* __restrict__ scale2,
                                                   float* __restrict__ shift2){
  const int blk = blockIdx.x, t = threadIdx.x;
  __shared__ float sw[256];
  __shared__ float r1[4], r2[4], r3[4];
  float csf = 0.f;
#pragma unroll
  for (int s = 0; s < 8; s++) csf += CSpart[s*256 + t];
  for (int sub = 0; sub < 4; sub++){
    const int c = blk*4 + sub;
    sw[t] = bf2f(W3bf[(size_t)c*512 + 256 + t]);
    __syncthreads();
    const float wj = sw[t];
    float dot = 0.f;
    const float* Grow = G + (size_t)t * 256;
    for (int k = 0; k < 256; k++) dot += sw[k] * Grow[k];
    float quad = wj * dot;
    float cdot = wj * csf;
    float uvv  = (t < 128) ? UVpart[(size_t)t * 512 + c] : 0.f;
    float a = quad, bq = cdot, cq = uvv;
#pragma unroll
    for (int m = 32; m >= 1; m >>= 1){
      a  += __shfl_xor(a, m); bq += __shfl_xor(bq, m); cq += __shfl_xor(cq, m);
    }
    if ((t & 63) == 0){ r1[t>>6] = a; r2[t>>6] = bq; r3[t>>6] = cq; }
    __syncthreads();
    if (t == 0){
      float wGw  = r1[0]+r1[1]+r1[2]+r1[3];
      float csw  = r2[0]+r2[1]+r2[2]+r2[3];
      float sUV  = r3[0]+r3[1]+r3[2]+r3[3];
      float sU = 0.f, sQ = 0.f;
#pragma unroll
      for (int s = 0; s < 8; s++){
        sU += Upart  [s*512 + c];
        sQ += Usqpart[s*512 + c];
      }
      const float invN = 1.0f / (float)R_;
      float mu = (csw + 32.f * sU) * invN;
      float e2 = (wGw + 2.f * sUV + 32.f * sQ) * invN;
      float var = e2 - mu * mu;
      float sc = rsqrtf(var + 1e-5f) * g2[c];
      scale2[c] = sc;
      shift2[c] = be2[c] - mu * sc;
    }
    __syncthreads();
  }
}

// ====== shared phase A: compute S2 tile (128 rows x 256 cols) into swizzled LDS ======
static __device__ __forceinline__ void phaseA_s2(const float* __restrict__ xyz,
                                                 const int* __restrict__ knnIdx,
                                                 const float4* __restrict__ F1c,
                                                 const ushortT* __restrict__ W2bf,
                                                 const float* __restrict__ b2,
                                                 ushortT* sS2, int blk,
                                                 int wv, int lr, int lg){
  bf16x8 a1[4];
  a1_frags(xyz, knnIdx, F1c, blk*128 + wv*16 + lr, lg, a1);
  f32x4 acc[16];
#pragma unroll
  for (int c = 0; c < 16; c++) acc[c] = (f32x4){0.f,0.f,0.f,0.f};
#pragma unroll
  for (int s = 0; s < 4; s++)
#pragma unroll
    for (int ct = 0; ct < 16; ct++){
      bf16x8 bb = *reinterpret_cast<const bf16x8*>(W2bf + (size_t)(ct*16+lr)*128 + s*32 + lg*8);
      acc[ct] = __builtin_amdgcn_mfma_f32_16x16x32_bf16(a1[s], bb, acc[ct], 0, 0, 0);
    }
#pragma unroll
  for (int ct = 0; ct < 16; ct++){
    int col = ct*16 + lr;
    float bb = b2[col];
#pragma unroll
    for (int i = 0; i < 4; i++){
      int row = wv*16 + lg*4 + i;
      sS2[row*256 + (col ^ ((row & 7) << 3))] = f2bf(acc[ct][i] + bb);
    }
  }
}

#define PHASE2(PASS, ACC)                                                               \
  {                                                                                     \
    _Pragma("unroll")                                                                   \
    for (int s = 0; s < 8; s++){                                                        \
      const int kk = s*32 + lg*8;                                                       \
      bf16x8 b0 = *reinterpret_cast<const bf16x8*>(                                     \
          W3bf + (size_t)((PASS)*256 + wv*32 + 0 + lr)*512 + 256 + kk);                 \
      bf16x8 b1 = *reinterpret_cast<const bf16x8*>(                                     \
          W3bf + (size_t)((PASS)*256 + wv*32 + 16 + lr)*512 + 256 + kk);                \
      _Pragma("unroll")                                                                 \
      for (int rf = 0; rf < 8; rf++){                                                   \
        int row = rf*16 + lr;                                                           \
        bf16x8 a = *reinterpret_cast<const bf16x8*>(                                    \
            &sS2[row*256 + (kk ^ ((row & 7) << 3))]);                                   \
        ACC[rf][0] = __builtin_amdgcn_mfma_f32_16x16x32_bf16(a, b0, ACC[rf][0], 0,0,0); \
        ACC[rf][1] = __builtin_amdgcn_mfma_f32_16x16x32_bf16(a, b1, ACC[rf][1], 0,0,0); \
      }                                                                                 \
    }                                                                                   \
  }

// ---------------- enc3 (FALLBACK): S2 -> S3 (+U) -> BN2 channel partials ----------------
__global__ __launch_bounds__(512) void enc3_kernel(const float* __restrict__ xyz,
                                                   const int* __restrict__ knnIdx,
                                                   const float4* __restrict__ F1c,
                                                   const ushortT* __restrict__ W2bf,
                                                   const float* __restrict__ b2,
                                                   const ushortT* __restrict__ W3bf,
                                                   const float* __restrict__ U,
                                                   float* __restrict__ P2sum,
                                                   float* __restrict__ P2sq){
  __shared__ ushortT sS2[128 * 256];
  const int blk = blockIdx.x;
  const int t = threadIdx.x, lane = t & 63, wv = t >> 6;
  const int lr = lane & 15, lg = lane >> 4;
  phaseA_s2(xyz, knnIdx, F1c, W2bf, b2, sS2, blk, wv, lr, lg);
  __syncthreads();
#pragma unroll
  for (int pass = 0; pass < 2; pass++){
    f32x4 acc[8][2];
#pragma unroll
    for (int rf = 0; rf < 8; rf++){ acc[rf][0] = (f32x4){0,0,0,0}; acc[rf][1] = (f32x4){0,0,0,0}; }
    PHASE2(pass, acc)
#pragma unroll
    for (int ct = 0; ct < 2; ct++){
      int col = pass*256 + wv*32 + ct*16 + lr;
      float s = 0.f, q = 0.f;
#pragma unroll
      for (int rf = 0; rf < 8; rf++){
        float uv = U[(size_t)(blk*4 + (rf >> 1)) * 512 + col];
#pragma unroll
        for (int i = 0; i < 4; i++){
          float v = acc[rf][ct][i] + uv;
          s += v; q += v * v;
        }
      }
      s += __shfl_xor(s, 16); s += __shfl_xor(s, 32);
      q += __shfl_xor(q, 16); q += __shfl_xor(q, 32);
      if (lg == 0){
        P2sum[(size_t)blk * 512 + col] = s;
        P2sq [(size_t)blk * 512 + col] = q;
      }
    }
  }
}

__global__ __launch_bounds__(256) void fin_kernel(const float* __restrict__ Psum,
                                                  const float* __restrict__ Psq,
                                                  int nPart, int C, float invN,
                                                  const float* __restrict__ g,
                                                  const float* __restrict__ be,
                                                  float* __restrict__ scale,
                                                  float* __restrict__ shift){
  const int ch = blockIdx.x, t = threadIdx.x;
  float s = 0.f, q = 0.f;
  for (int i = t; i < nPart; i += 256){
    s += Psum[(size_t)i * C + ch];
    q += Psq [(size_t)i * C + ch];
  }
  __shared__ float ls[4], lq[4];
#pragma unroll
  for (int m = 32; m >= 1; m >>= 1){ s += __shfl_xor(s, m); q += __shfl_xor(q, m); }
  if ((t & 63) == 0){ ls[t >> 6] = s; lq[t >> 6] = q; }
  __syncthreads();
  if (t == 0){
    s = ls[0] + ls[1] + ls[2] + ls[3];
    q = lq[0] + lq[1] + lq[2] + lq[3];
    float mu = s * invN;
    float var = q * invN - mu * mu;
    float sc = rsqrtf(var + 1e-5f) * g[ch];
    scale[ch] = sc;
    shift[ch] = be[ch] - mu * sc;
  }
}

// ====== enc4 epilogue shared by both variants (S2 already in sS2) ======
#define ENC4_BODY                                                                       \
  f32x4 acc0[8][2], acc1[8][2];                                                         \
  _Pragma("unroll")                                                                     \
  for (int rf = 0; rf < 8; rf++){                                                       \
    acc0[rf][0] = (f32x4){0,0,0,0}; acc0[rf][1] = (f32x4){0,0,0,0};                     \
    acc1[rf][0] = (f32x4){0,0,0,0}; acc1[rf][1] = (f32x4){0,0,0,0};                     \
  }                                                                                     \
  PHASE2(0, acc0)                                                                       \
  PHASE2(1, acc1)                                                                       \
  __syncthreads();                                                                      \
  f32x4 accF[8];                                                                        \
  _Pragma("unroll")                                                                     \
  for (int rf = 0; rf < 8; rf++) accF[rf] = (f32x4){0,0,0,0};                           \
  _Pragma("unroll")                                                                     \
  for (int ct = 0; ct < 2; ct++){                                                       \
    int colh = wv*32 + ct*16 + lr;                                                      \
    _Pragma("unroll")                                                                   \
    for (int rf = 0; rf < 8; rf++){                                                     \
      float uv = U[(size_t)(blk*4 + (rf >> 1)) * 512 + colh];                           \
      _Pragma("unroll")                                                                 \
      for (int i = 0; i < 4; i++){                                                      \
        int row = rf*16 + lg*4 + i;                                                     \
        float v = acc0[rf][ct][i] + uv;                                                 \
        sS2[row*256 + (colh ^ ((row & 7) << 3))] =                                      \
            f2bf(fmaxf(fmaf(v, s_sc[colh], s_sh[colh]), 0.f));                          \
      }                                                                                 \
    }                                                                                   \
  }                                                                                     \
  __syncthreads();                                                                      \
  _Pragma("unroll")                                                                     \
  for (int s = 0; s < 8; s++){                                                          \
    const int kk = s*32 + lg*8;                                                         \
    bf16x8 b = *reinterpret_cast<const bf16x8*>(W4bf + (size_t)(wv*16 + lr)*512 + kk);  \
    _Pragma("unroll")                                                                   \
    for (int rf = 0; rf < 8; rf++){                                                     \
      int row = rf*16 + lr;                                                             \
      bf16x8 a = *reinterpret_cast<const bf16x8*>(&sS2[row*256 + (kk ^ ((row & 7) << 3))]); \
      accF[rf] = __builtin_amdgcn_mfma_f32_16x16x32_bf16(a, b, accF[rf], 0, 0, 0);      \
    }                                                                                   \
  }                                                                                     \
  __syncthreads();                                                                      \
  _Pragma("unroll")                                                                     \
  for (int ct = 0; ct < 2; ct++){                                                       \
    int colh = wv*32 + ct*16 + lr;                                                      \
    int col  = 256 + colh;                                                              \
    _Pragma("unroll")                                                                   \
    for (int rf = 0; rf < 8; rf++){                                                     \
      float uv = U[(size_t)(blk*4 + (rf >> 1)) * 512 + col];                            \
      _Pragma("unroll")                                                                 \
      for (int i = 0; i < 4; i++){                                                      \
        int row = rf*16 + lg*4 + i;                                                     \
        float v = acc1[rf][ct][i] + uv;                                                 \
        sS2[row*256 + (colh ^ ((row & 7) << 3))] =                                      \
            f2bf(fmaxf(fmaf(v, s_sc[col], s_sh[col]), 0.f));                            \
      }                                                                                 \
    }                                                                                   \
  }                                                                                     \
  __syncthreads();                                                                      \
  _Pragma("unroll")                                                                     \
  for (int s = 0; s < 8; s++){                                                          \
    const int kk = s*32 + lg*8;                                                         \
    bf16x8 b = *reinterpret_cast<const bf16x8*>(W4bf + (size_t)(wv*16 + lr)*512 + 256 + kk); \
    _Pragma("unroll")                                                                   \
    for (int rf = 0; rf < 8; rf++){                                                     \
      int row = rf*16 + lr;                                                             \
      bf16x8 a = *reinterpret_cast<const bf16x8*>(&sS2[row*256 + (kk ^ ((row & 7) << 3))]); \
      accF[rf] = __builtin_amdgcn_mfma_f32_16x16x32_bf16(a, b, accF[rf], 0, 0, 0);      \
    }                                                                                   \
  }                                                                                     \
  const float bb4 = b4[wv*16 + lr];                                                     \
  _Pragma("unroll")                                                                     \
  for (int gl = 0; gl < 4; gl++){                                                       \
    float m = -3.0e38f;                                                                 \
    _Pragma("unroll")                                                                   \
    for (int i = 0; i < 4; i++){                                                        \
      m = fmaxf(m, accF[2*gl    ][i]);                                                  \
      m = fmaxf(m, accF[2*gl + 1][i]);                                                  \
    }                                                                                   \
    m = fmaxf(m, __shfl_xor(m, 16));                                                    \
    m = fmaxf(m, __shfl_xor(m, 32));                                                    \
    if (lg == 0)                                                                        \
      feat[((size_t)blk*4 + gl)*128 + wv*16 + lr] = m + bb4;                            \
  }

// ---------------- enc4 (FALLBACK): recompute S2, then epilogue ----------------
__global__ __launch_bounds__(512) void enc4_kernel(const float* __restrict__ xyz,
                                                   const int* __restrict__ knnIdx,
                                                   const float4* __restrict__ F1c,
                                                   const ushortT* __restrict__ W2bf,
                                                   const float* __restrict__ b2,
                                                   const ushortT* __restrict__ W3bf,
                                                   const float* __restrict__ U,
                                                   const float* __restrict__ scale2,
                                                   const float* __restrict__ shift2,
                                                   const ushortT* __restrict__ W4bf,
                                                   const float* __restrict__ b4,
                                                   float* __restrict__ feat){
  __shared__ ushortT sS2[128 * 256];
  __shared__ float s_sc[512], s_sh[512];
  const int blk = blockIdx.x;
  const int t = threadIdx.x, lane = t & 63, wv = t >> 6;
  const int lr = lane & 15, lg = lane >> 4;
  if (t < 512){ s_sc[t] = scale2[t]; s_sh[t] = shift2[t]; }
  phaseA_s2(xyz, knnIdx, F1c, W2bf, b2, sS2, blk, wv, lr, lg);
  __syncthreads();
  ENC4_BODY
}

// ---------------- enc4r (S2 PATH): load S2 tile from global, then epilogue ----------------
__global__ __launch_bounds__(512) void enc4r_kernel(const ushortT* __restrict__ S2g,
                                                    const ushortT* __restrict__ W3bf,
                                                    const float* __restrict__ U,
                                                    const float* __restrict__ scale2,
                                                    const float* __restrict__ shift2,
                                                    const ushortT* __restrict__ W4bf,
                                                    const float* __restrict__ b4,
                                                    float* __restrict__ feat){
  __shared__ ushortT sS2[128 * 256];
  __shared__ float s_sc[512], s_sh[512];
  const int blk = blockIdx.x;
  const int t = threadIdx.x, lane = t & 63, wv = t >> 6;
  const int lr = lane & 15, lg = lane >> 4;
  if (t < 512){ s_sc[t] = scale2[t]; s_sh[t] = shift2[t]; }
  {
    const uint4* src = reinterpret_cast<const uint4*>(S2g + (size_t)blk * 32768);
    uint4* dst = reinterpret_cast<uint4*>(sS2);
#pragma unroll
    for (int i = 0; i < 8; i++) dst[t + i*512] = src[t + i*512];
  }
  __syncthreads();
  ENC4_BODY
}

extern "C" void kernel_launch(void* const* d_in, const int* in_sizes, int n_in,
                              void* d_out, int out_size, void* d_ws, size_t ws_size,
                              hipStream_t stream){
  const float* xyz = (const float*)d_in[0];
  const float* W1  = (const float*)d_in[1];
  const float* b1  = (const float*)d_in[2];
  const float* g1  = (const float*)d_in[3];
  const float* be1 = (const float*)d_in[4];
  const float* W2  = (const float*)d_in[5];
  const float* b2  = (const float*)d_in[6];
  const float* W3  = (const float*)d_in[7];
  const float* b3  = (const float*)d_in[8];
  const float* g2  = (const float*)d_in[9];
  const float* be2 = (const float*)d_in[10];
  const float* W4  = (const float*)d_in[11];
  const float* b4  = (const float*)d_in[12];

  float* out = (float*)d_out;
  float* center = out;                         // (16,512,3)
  float* feat   = out + (size_t)B_ * G_ * 3;   // (16,512,128)

  char* p = (char*)d_ws;
  size_t used = 0;
  auto alloc = [&](size_t bytes) -> char* {
    char* r = p + used; used += (bytes + 255) & ~(size_t)255; return r;
  };
  // ---- common allocations (~22 MB) ----
  int*     knnIdx = (int*)    alloc((size_t)R_ * 4);           // 1 MB
  ushortT* W2bf   = (ushortT*)alloc(32768 * 2);
  ushortT* W3bf   = (ushortT*)alloc(262144 * 2);
  ushortT* W4bf   = (ushortT*)alloc(65536 * 2);
  float4*  F1c    = (float4*) alloc(128 * 16);
  float*   Mpart  = (float*)  alloc(256 * 9 * 4);
  ushortT* fg     = (ushortT*)alloc((size_t)M_ * 256 * 2);     // 4 MB
  float*   U      = (float*)  alloc((size_t)M_ * 512 * 4);     // 16 MB
  float*   scale2 = (float*)  alloc(512 * 4);
  float*   shift2 = (float*)  alloc(512 * 4);

  // ---- S2-materialization gate (r8/r9: NBG>0 path ran and won) ----
  const size_t s2_b    = (size_t)R_ * 256 * 2;                 // 128 MB
  const size_t fgsum_b = (size_t)M_ * 256 * 4;                 // 8 MB
  const size_t small_b = (256*1024) + (256*1024) + (64*1024);  // UVpart + G + parts
  const size_t margin  = 4u << 20;
  int NBG = 0;
  if      (ws_size >= used + s2_b + fgsum_b + small_b + (size_t)256*65536*4 + margin) NBG = 256;
  else if (ws_size >= used + s2_b + fgsum_b + small_b + (size_t)128*65536*4 + margin) NBG = 128;
  else if (ws_size >= used + s2_b + fgsum_b + small_b + (size_t)64 *65536*4 + margin) NBG = 64;

  cast3_kernel  <<<dim3(1024), dim3(256),  0, stream>>>(W2, W3, W4, W2bf, W3bf, W4bf);
  fps_kernel    <<<dim3(B_),   dim3(512),  0, stream>>>(xyz, center);
  knn_kernel    <<<dim3(M_),   dim3(256),  0, stream>>>(xyz, center, knnIdx);
  moments_kernel<<<dim3(256),  dim3(256),  0, stream>>>(xyz, knnIdx, Mpart);
  prep1_kernel  <<<dim3(1),    dim3(128),  0, stream>>>(Mpart, W1, b1, g1, be1, F1c);

  if (NBG){
    float*   fgsum   = (float*)  alloc(fgsum_b);
    ushortT* S2g     = (ushortT*)alloc(s2_b);
    float*   UVpart  = (float*)  alloc(128 * 512 * 4);
    float*   G       = (float*)  alloc(65536 * 4);
    float*   Upart   = (float*)  alloc(8 * 512 * 4);
    float*   Usqpart = (float*)  alloc(8 * 512 * 4);
    float*   CSpart  = (float*)  alloc(8 * 256 * 4);
    float*   Gpart   = (float*)  alloc((size_t)NBG * 65536 * 4);
    enc2s_kernel<<<dim3(2048), dim3(512), 0, stream>>>(xyz, knnIdx, F1c, W2bf, b2, fg, fgsum, S2g);
    u_kernel    <<<dim3(512),  dim3(256), 0, stream>>>(fg, W3bf, b3, U);
    v_kernel    <<<dim3(512),  dim3(256), 0, stream>>>(fgsum, W3bf, U, UVpart);
    gram2_kernel<<<dim3(NBG),  dim3(512), 0, stream>>>(S2g, Gpart, 2048/NBG);
    gred_kernel <<<dim3(256),  dim3(256), 0, stream>>>(Gpart, G, NBG);
    ured_kernel <<<dim3(64),   dim3(256), 0, stream>>>(U, fgsum, Upart, Usqpart, CSpart);
    fin2_kernel <<<dim3(128),  dim3(256), 0, stream>>>(G, CSpart, Upart, Usqpart, UVpart,
                                                       W3bf, g2, be2, scale2, shift2);
    enc4r_kernel<<<dim3(2048), dim3(512), 0, stream>>>(S2g, W3bf, U, scale2, shift2, W4bf, b4, feat);
  } else {
    float* P2sum = (float*)alloc((size_t)2048 * 512 * 4);      // 4 MB
    float* P2sq  = (float*)alloc((size_t)2048 * 512 * 4);      // 4 MB
    f2g_kernel <<<dim3(4096), dim3(256), 0, stream>>>(xyz, knnIdx, F1c, W2bf, b2, fg);
    u_kernel   <<<dim3(512),  dim3(256), 0, stream>>>(fg, W3bf, b3, U);
    enc3_kernel<<<dim3(2048), dim3(512), 0, stream>>>(xyz, knnIdx, F1c, W2bf, b2, W3bf, U, P2sum, P2sq);
    fin_kernel <<<dim3(512),  dim3(256), 0, stream>>>(P2sum, P2sq, 2048, 512, 1.0f/(float)R_,
                                                      g2, be2, scale2, shift2);
    enc4_kernel<<<dim3(2048), dim3(512), 0, stream>>>(xyz, knnIdx, F1c, W2bf, b2, W3bf, U,
                                                      scale2, shift2, W4bf, b4, feat);
  }
}

// Round 11
// 1553.156 us; speedup vs baseline: 1.0729x; 1.0729x over previous
//
#include <hip/hip_runtime.h>

typedef unsigned short ushortT;
typedef unsigned int uintT;
typedef unsigned long long u64T;
typedef __bf16 bf16x8 __attribute__((ext_vector_type(8)));
typedef float f32x4 __attribute__((ext_vector_type(4)));

#define B_ 16
#define N_ 8192
#define G_ 512
#define KNN_ 32
#define M_ (B_*G_)      // 8192 groups
#define R_ (M_*KNN_)    // 262144 rows

static __device__ __forceinline__ ushortT f2bf(float f){
  uintT u = __float_as_uint(f);
  return (ushortT)((u + 0x7fffu + ((u >> 16) & 1u)) >> 16);
}
static __device__ __forceinline__ float bf2f(ushortT h){ return __uint_as_float(((uintT)h) << 16); }

union U16 { uint4 u; ushortT s[8]; bf16x8 v; };

// u64 max with butterfly partner via ds_swizzle (masks 1..16, within 32-lane halves)
#define SWZ_MAX(vv, pat) {                                              \
    uintT lo_ = (uintT)(vv), hi_ = (uintT)((vv) >> 32);                 \
    uintT olo_ = (uintT)__builtin_amdgcn_ds_swizzle((int)lo_, (pat));   \
    uintT ohi_ = (uintT)__builtin_amdgcn_ds_swizzle((int)hi_, (pat));   \
    u64T o_ = ((u64T)ohi_ << 32) | olo_;                                \
    (vv) = (o_ > (vv)) ? o_ : (vv); }

// ---------------- FPS: exact fp32 replication, 1 block/batch, 512 thr, lean reductions ------
// (round-9 proven: 525us) Selection bit-identical: same _rn ops in same order; max over u64
// keys (distbits<<32)|~p is order-independent; ties resolved by key (lowest p wins).
__global__ __launch_bounds__(512) void fps_kernel(const float* __restrict__ xyz,
                                                  float* __restrict__ center){
  const int b = blockIdx.x;
  const int tid = threadIdx.x;                   // 512 threads = 8 waves
  const float* P = xyz + (size_t)b * N_ * 3;
  __shared__ float sx[N_], sy[N_], sz[N_];       // 96 KB
  __shared__ u64T slot[2][8];
  float px[16], py[16], pz[16], dist[16];
  uintT nI[16];
#pragma unroll
  for (int k = 0; k < 16; k++){
    int p = tid + (k << 9);
    float x = P[p*3+0], y = P[p*3+1], z = P[p*3+2];
    sx[p] = x; sy[p] = y; sz[p] = z;
    px[k] = x; py[k] = y; pz[k] = z;
    dist[k] = 1e10f;
    nI[k] = ~(uintT)p;
  }
  __syncthreads();
  const int lane = tid & 63, wv = tid >> 6;
  int far = 0;
  for (int s = 0; s < G_; s++){
    const float cx = sx[far], cy = sy[far], cz = sz[far];
    if (tid == 0){
      float* co = center + ((size_t)b * G_ + s) * 3;
      co[0] = cx; co[1] = cy; co[2] = cz;
    }
    u64T pk[16];
#pragma unroll
    for (int k = 0; k < 16; k++){
      float d0 = __fsub_rn(px[k], cx), d1 = __fsub_rn(py[k], cy), d2 = __fsub_rn(pz[k], cz);
      float d  = __fadd_rn(__fadd_rn(__fmul_rn(d0,d0), __fmul_rn(d1,d1)), __fmul_rn(d2,d2));
      float dd = fminf(dist[k], d);
      dist[k] = dd;
      pk[k] = ((u64T)__float_as_uint(dd) << 32) | nI[k];
    }
#pragma unroll
    for (int st = 8; st >= 1; st >>= 1)
#pragma unroll
      for (int k = 0; k < st; k++)
        pk[k] = (pk[k + st] > pk[k]) ? pk[k + st] : pk[k];
    u64T best = pk[0];
    SWZ_MAX(best, 0x041F)       // xor 1
    SWZ_MAX(best, 0x081F)       // xor 2
    SWZ_MAX(best, 0x101F)       // xor 4
    SWZ_MAX(best, 0x201F)       // xor 8
    SWZ_MAX(best, 0x401F)       // xor 16
    {
      u64T o = __shfl_xor(best, 32);
      best = (o > best) ? o : best;
    }
    if (lane == 0) slot[s & 1][wv] = best;
    __syncthreads();
    u64T v = slot[s & 1][lane & 7];
    SWZ_MAX(v, 0x041F)
    SWZ_MAX(v, 0x081F)
    SWZ_MAX(v, 0x101F)
    far = (int)(~(uintT)v) & (N_ - 1);
  }
}

// ---------------- kNN: per-wave barrier-free extraction + single merge (round-4) ------------
__global__ __launch_bounds__(256) void knn_kernel(const float* __restrict__ xyz,
                                                  const float* __restrict__ center,
                                                  int* __restrict__ knnIdx){
  const int mc = blockIdx.x;
  const int b  = mc >> 9;
  const int tid = threadIdx.x;
  const int lane = tid & 63, w = tid >> 6;
  const float* P = xyz + (size_t)b * N_ * 3;
  const float cx = center[mc*3+0], cy = center[mc*3+1], cz = center[mc*3+2];
  const float tc = __fadd_rn(__fadd_rn(__fmul_rn(cx,cx), __fmul_rn(cy,cy)), __fmul_rn(cz,cz));
  uintT key[32];
  uintT bd = 0xFFFFFFFFu; int bk = 0;
#pragma unroll
  for (int k = 0; k < 32; k++){
    int p = tid + (k << 8);
    float x = P[p*3+0], y = P[p*3+1], z = P[p*3+2];
    float tx  = __fadd_rn(__fadd_rn(__fmul_rn(x,x), __fmul_rn(y,y)), __fmul_rn(z,z));
    float dot = __fadd_rn(__fadd_rn(__fmul_rn(cx,x), __fmul_rn(cy,y)), __fmul_rn(cz,z));
    float d   = __fsub_rn(__fadd_rn(tc, tx), __fmul_rn(2.0f, dot));
    uintT bb  = __float_as_uint(d);
    uintT kk  = bb ^ ((uintT)((int)bb >> 31) | 0x80000000u);   // monotone map
    key[k] = kk;
    if (kk < bd){ bd = kk; bk = k; }
  }
  __shared__ u64T sKeys[128];
  for (int r = 0; r < KNN_; r++){
    u64T me = ((u64T)bd << 32) | (uintT)(tid + (bk << 8));
    u64T m = me;
#pragma unroll
    for (int msk = 32; msk >= 1; msk >>= 1){
      u64T o = __shfl_xor(m, msk);
      m = (o < m) ? o : m;
    }
    if (lane == 0) sKeys[w * 32 + r] = m;
    if (me == m){
      uintT nb = 0xFFFFFFFFu; int nk = 0;
#pragma unroll
      for (int k = 0; k < 32; k++){
        uintT vv = (k == bk) ? 0xFFFFFFFFu : key[k];
        key[k] = vv;
        if (vv < nb){ nb = vv; nk = k; }
      }
      bd = nb; bk = nk;
    }
  }
  __syncthreads();
  if (w == 0){
    u64T e0 = sKeys[lane], e1 = sKeys[lane + 64];
    for (int r = 0; r < KNN_; r++){
      u64T be = (e0 < e1) ? e0 : e1;
      u64T m = be;
#pragma unroll
      for (int msk = 32; msk >= 1; msk >>= 1){
        u64T o = __shfl_xor(m, msk);
        m = (o < m) ? o : m;
      }
      if (lane == 0) knnIdx[(size_t)mc * KNN_ + r] = (int)(uintT)m;
      if (be == m){
        if (e0 == m) e0 = ~0ull; else e1 = ~0ull;
      }
    }
  }
}

// ---------------- moments + prep1: BN1 analytic stats ----------------
__global__ __launch_bounds__(256) void moments_kernel(const float* __restrict__ xyz,
                                                      const int* __restrict__ knnIdx,
                                                      float* __restrict__ Mpart){
  const int t = threadIdx.x, blk = blockIdx.x;
  float m[9];
#pragma unroll
  for (int k = 0; k < 9; k++) m[k] = 0.f;
  for (int i = 0; i < 4; i++){
    int row = blk * 1024 + i * 256 + t;
    int p = knnIdx[row];
    int b = row >> 14;
    const float* pt = xyz + ((size_t)(b * N_ + p)) * 3;
    float x = pt[0], y = pt[1], z = pt[2];
    m[0]+=x; m[1]+=y; m[2]+=z; m[3]+=x*x; m[4]+=y*y; m[5]+=z*z; m[6]+=x*y; m[7]+=x*z; m[8]+=y*z;
  }
  __shared__ float red[4][9];
  const int lane = t & 63, w = t >> 6;
#pragma unroll
  for (int k = 0; k < 9; k++){
    float v = m[k];
#pragma unroll
    for (int sh = 32; sh >= 1; sh >>= 1) v += __shfl_xor(v, sh);
    if (lane == 0) red[w][k] = v;
  }
  __syncthreads();
  if (t < 9) Mpart[blk * 9 + t] = red[0][t] + red[1][t] + red[2][t] + red[3][t];
}

__global__ __launch_bounds__(128) void prep1_kernel(const float* __restrict__ Mpart,
                                                    const float* __restrict__ W1,
                                                    const float* __restrict__ b1,
                                                    const float* __restrict__ g1,
                                                    const float* __restrict__ be1,
                                                    float4* __restrict__ F1c){
  __shared__ float S[9];
  const int t = threadIdx.x;
  if (t < 9){
    float s = 0.f;
    for (int i = 0; i < 256; i++) s += Mpart[i * 9 + t];
    S[t] = s;
  }
  __syncthreads();
  const float invN = 1.0f / (float)R_;
  float mx = S[0]*invN, my = S[1]*invN, mz = S[2]*invN;
  float Cxx = S[3]*invN - mx*mx, Cyy = S[4]*invN - my*my, Czz = S[5]*invN - mz*mz;
  float Cxy = S[6]*invN - mx*my, Cxz = S[7]*invN - mx*mz, Cyz = S[8]*invN - my*mz;
  const int ch = t;
  float w0 = W1[ch*3+0], w1 = W1[ch*3+1], w2 = W1[ch*3+2], bb = b1[ch];
  float var = w0*w0*Cxx + w1*w1*Cyy + w2*w2*Czz + 2.f*(w0*w1*Cxy + w0*w2*Cxz + w1*w2*Cyz);
  float mu  = w0*mx + w1*my + w2*mz + bb;
  float sc  = rsqrtf(var + 1e-5f) * g1[ch];
  float sh  = be1[ch] - mu * sc;
  F1c[ch] = make_float4(w0*sc, w1*sc, w2*sc, fmaf(bb, sc, sh));
}

__global__ __launch_bounds__(256) void cast3_kernel(const float* __restrict__ W2,
                                                    const float* __restrict__ W3,
                                                    const float* __restrict__ W4,
                                                    ushortT* W2b, ushortT* W3b, ushortT* W4b){
  int i = blockIdx.x * 256 + threadIdx.x;
  if (i < 32768)  W2b[i] = f2bf(W2[i]);
  if (i < 262144) W3b[i] = f2bf(W3[i]);
  if (i < 65536)  W4b[i] = f2bf(W4[i]);
}

// ---------------- per-lane layer-1 A fragments (no LDS): 4 x bf16x8 ----------------
static __device__ __forceinline__ void a1_frags(const float* __restrict__ xyz,
                                                const int* __restrict__ knnIdx,
                                                const float4* __restrict__ F1c,
                                                int row, int lg, bf16x8 fr[4]){
  const int p = knnIdx[row];
  const int b = row >> 14;
  const float* pt = xyz + ((size_t)(b * N_ + p)) * 3;
  const float x = pt[0], y = pt[1], z = pt[2];
#pragma unroll
  for (int s = 0; s < 4; s++){
    U16 u;
#pragma unroll
    for (int j = 0; j < 8; j++){
      const float4 f = F1c[s * 32 + lg * 8 + j];
      const float h = fmaxf(fmaf(x, f.x, fmaf(y, f.y, fmaf(z, f.z, f.w))), 0.f);
      u.s[j] = f2bf(h);
    }
    fr[s] = u.v;
  }
}

// ---------------- f2g (FALLBACK): per-64-row tile, fg only ----------------
__global__ __launch_bounds__(256) void f2g_kernel(const float* __restrict__ xyz,
                                                  const int* __restrict__ knnIdx,
                                                  const float4* __restrict__ F1c,
                                                  const ushortT* __restrict__ W2bf,
                                                  const float* __restrict__ b2,
                                                  ushortT* __restrict__ fg){
  const int rc = blockIdx.x;
  const int t = threadIdx.x, lane = t & 63, w = t >> 6;
  const int lr = lane & 15, lg = lane >> 4;
  const int row = rc * 64 + w * 16 + lr;
  bf16x8 a1[4];
  a1_frags(xyz, knnIdx, F1c, row, lg, a1);
  f32x4 acc[16];
#pragma unroll
  for (int c = 0; c < 16; c++) acc[c] = (f32x4){0.f,0.f,0.f,0.f};
#pragma unroll
  for (int s = 0; s < 4; s++)
#pragma unroll
    for (int ct = 0; ct < 16; ct++){
      bf16x8 bb = *reinterpret_cast<const bf16x8*>(W2bf + (size_t)(ct*16+lr)*128 + s*32 + lg*8);
      acc[ct] = __builtin_amdgcn_mfma_f32_16x16x32_bf16(a1[s], bb, acc[ct], 0, 0, 0);
    }
  __shared__ float wmax[4][256];
#pragma unroll
  for (int ct = 0; ct < 16; ct++){
    float cmax = fmaxf(fmaxf(acc[ct][0], acc[ct][1]), fmaxf(acc[ct][2], acc[ct][3]));
    cmax = fmaxf(cmax, __shfl_xor(cmax, 16));
    cmax = fmaxf(cmax, __shfl_xor(cmax, 32));
    if (lg == 0) wmax[w][ct*16+lr] = cmax;
  }
  __syncthreads();
  {
    float bb = b2[t];
    fg[((size_t)rc*2 + 0)*256 + t] = f2bf(fmaxf(wmax[0][t], wmax[1][t]) + bb);
    fg[((size_t)rc*2 + 1)*256 + t] = f2bf(fmaxf(wmax[2][t], wmax[3][t]) + bb);
  }
}

// ---------------- enc2s (S2 PATH): phaseA + fg + fgsum + S2 -> global (swizzled layout) -----
__global__ __launch_bounds__(512) void enc2s_kernel(const float* __restrict__ xyz,
                                                    const int* __restrict__ knnIdx,
                                                    const float4* __restrict__ F1c,
                                                    const ushortT* __restrict__ W2bf,
                                                    const float* __restrict__ b2,
                                                    ushortT* __restrict__ fg,
                                                    float* __restrict__ fgsum,
                                                    ushortT* __restrict__ S2g){
  __shared__ ushortT sS2[128 * 256];           // 64 KB
  __shared__ float wmax[8][256];               // 8 KB
  __shared__ float wsum[8][256];               // 8 KB
  const int blk = blockIdx.x;                  // 2048 tiles of 128 rows = 4 groups
  const int t = threadIdx.x, lane = t & 63, wv = t >> 6;
  const int lr = lane & 15, lg = lane >> 4;
  bf16x8 a1[4];
  a1_frags(xyz, knnIdx, F1c, blk*128 + wv*16 + lr, lg, a1);
  f32x4 acc[16];
#pragma unroll
  for (int c = 0; c < 16; c++) acc[c] = (f32x4){0.f,0.f,0.f,0.f};
#pragma unroll
  for (int s = 0; s < 4; s++)
#pragma unroll
    for (int ct = 0; ct < 16; ct++){
      bf16x8 bb = *reinterpret_cast<const bf16x8*>(W2bf + (size_t)(ct*16+lr)*128 + s*32 + lg*8);
      acc[ct] = __builtin_amdgcn_mfma_f32_16x16x32_bf16(a1[s], bb, acc[ct], 0, 0, 0);
    }
#pragma unroll
  for (int ct = 0; ct < 16; ct++){
    const int col = ct*16 + lr;
    const float bb = b2[col];
    float cmax = -3.0e38f, csum = 0.f;
#pragma unroll
    for (int i = 0; i < 4; i++){
      int row = wv*16 + lg*4 + i;
      ushortT sv = f2bf(acc[ct][i] + bb);
      sS2[row*256 + (col ^ ((row & 7) << 3))] = sv;
      csum += bf2f(sv);
      cmax = fmaxf(cmax, acc[ct][i]);          // raw acc; bias added at emission (r4 semantics)
    }
    cmax = fmaxf(cmax, __shfl_xor(cmax, 16));
    cmax = fmaxf(cmax, __shfl_xor(cmax, 32));
    csum += __shfl_xor(csum, 16); csum += __shfl_xor(csum, 32);
    if (lg == 0){ wmax[wv][col] = cmax; wsum[wv][col] = csum; }
  }
  __syncthreads();
#pragma unroll
  for (int q = 0; q < 2; q++){
    int gl = q*2 + (t >> 8);                   // 0..3
    int col = t & 255;
    float bb = b2[col];
    fg   [((size_t)blk*4 + gl)*256 + col] = f2bf(fmaxf(wmax[2*gl][col], wmax[2*gl+1][col]) + bb);
    fgsum[((size_t)blk*4 + gl)*256 + col] = wsum[2*gl][col] + wsum[2*gl+1][col];
  }
  // copy S2 tile out (linear copy preserves swizzled layout)
  const uint4* src = reinterpret_cast<const uint4*>(sS2);
  uint4* dst = reinterpret_cast<uint4*>(S2g + (size_t)blk * 32768);
#pragma unroll
  for (int i = 0; i < 8; i++) dst[t + i*512] = src[t + i*512];
}

// ---------------- u: U = fg @ W3a^T + b3 (8192 x 512, K=256) ----------------
__global__ __launch_bounds__(256) void u_kernel(const ushortT* __restrict__ fg,
                                                const ushortT* __restrict__ W3bf,
                                                const float* __restrict__ b3,
                                                float* __restrict__ U){
  const int bid = blockIdx.x;
  const int rc = bid >> 2, cc = bid & 3;
  const int t = threadIdx.x, lane = t & 63, w = t >> 6;
  const int lr = lane & 15, lg = lane >> 4;
  const int arow = rc * 64 + w * 16 + lr;
  f32x4 acc[8];
#pragma unroll
  for (int c = 0; c < 8; c++) acc[c] = (f32x4){0.f,0.f,0.f,0.f};
#pragma unroll
  for (int s = 0; s < 8; s++){
    bf16x8 a = *reinterpret_cast<const bf16x8*>(fg + (size_t)arow*256 + s*32 + lg*8);
#pragma unroll
    for (int ct = 0; ct < 8; ct++){
      bf16x8 bb = *reinterpret_cast<const bf16x8*>(W3bf + (size_t)(cc*128+ct*16+lr)*512 + s*32 + lg*8);
      acc[ct] = __builtin_amdgcn_mfma_f32_16x16x32_bf16(a, bb, acc[ct], 0, 0, 0);
    }
  }
#pragma unroll
  for (int ct = 0; ct < 8; ct++){
    int col = cc*128 + ct*16 + lr;
    float bb = b3[col];
#pragma unroll
    for (int i = 0; i < 4; i++){
      int crow = rc*64 + w*16 + lg*4 + i;
      U[(size_t)crow * 512 + col] = acc[ct][i] + bb;
    }
  }
}

// ---------------- v: V = bf16(fgsum) @ W3b^T; per-block UV partials (r5-verified) ----------
__global__ __launch_bounds__(256) void v_kernel(const float* __restrict__ fgsum,
                                                const ushortT* __restrict__ W3bf,
                                                const float* __restrict__ U,
                                                float* __restrict__ UVpart){
  const int bid = blockIdx.x;
  const int rc = bid >> 2, cc = bid & 3;
  const int t = threadIdx.x, lane = t & 63, w = t >> 6;
  const int lr = lane & 15, lg = lane >> 4;
  const int arow = rc * 64 + w * 16 + lr;
  f32x4 acc[8];
#pragma unroll
  for (int c = 0; c < 8; c++) acc[c] = (f32x4){0.f,0.f,0.f,0.f};
#pragma unroll
  for (int s = 0; s < 8; s++){
    int kk = s*32 + lg*8;
    float4 fa = *reinterpret_cast<const float4*>(&fgsum[(size_t)arow*256 + kk]);
    float4 fb = *reinterpret_cast<const float4*>(&fgsum[(size_t)arow*256 + kk + 4]);
    U16 ua;
    ua.s[0]=f2bf(fa.x); ua.s[1]=f2bf(fa.y); ua.s[2]=f2bf(fa.z); ua.s[3]=f2bf(fa.w);
    ua.s[4]=f2bf(fb.x); ua.s[5]=f2bf(fb.y); ua.s[6]=f2bf(fb.z); ua.s[7]=f2bf(fb.w);
#pragma unroll
    for (int ct = 0; ct < 8; ct++){
      bf16x8 bb = *reinterpret_cast<const bf16x8*>(W3bf + (size_t)(cc*128+ct*16+lr)*512 + 256 + kk);
      acc[ct] = __builtin_amdgcn_mfma_f32_16x16x32_bf16(ua.v, bb, acc[ct], 0, 0, 0);
    }
  }
  __shared__ float sUV[4][128];
#pragma unroll
  for (int ct = 0; ct < 8; ct++){
    int col = cc*128 + ct*16 + lr;
    float uv = 0.f;
#pragma unroll
    for (int i = 0; i < 4; i++){
      int g = rc*64 + w*16 + lg*4 + i;
      uv += acc[ct][i] * U[(size_t)g * 512 + col];
    }
    uv += __shfl_xor(uv, 16); uv += __shfl_xor(uv, 32);
    if (lg == 0) sUV[w][ct*16+lr] = uv;
  }
  __syncthreads();
  if (t < 128)
    UVpart[(size_t)rc * 512 + cc*128 + t] = sUV[0][t] + sUV[1][t] + sUV[2][t] + sUV[3][t];
}

// ---------------- gram2 (S2 PATH): G partials from materialized S2 (no phaseA, no spill) ----
__global__ __launch_bounds__(512) void gram2_kernel(const ushortT* __restrict__ S2g,
                                                    float* __restrict__ Gpart,
                                                    int tilesPerBlk){
  __shared__ ushortT sT[256 * 136];            // 69.6 KB transposed [col][row], +8 pad
  const int blk = blockIdx.x;
  const int t = threadIdx.x, lane = t & 63, wv = t >> 6;
  const int lr = lane & 15, lg = lane >> 4;
  f32x4 gacc[32];
#pragma unroll
  for (int c = 0; c < 32; c++) gacc[c] = (f32x4){0.f,0.f,0.f,0.f};
  const int r  = t >> 2;
  const int cb = (t & 3) * 64;
  for (int tile = 0; tile < tilesPerBlk; tile++){
    const int rt = blk * tilesPerBlk + tile;
    __syncthreads();                           // prev tile's MFMA reads complete
    const int swz = (r & 7) << 3;
#pragma unroll
    for (int u4 = 0; u4 < 8; u4++){
      int sc0 = cb + u4*8;                     // stored (swizzled) col index, 8-aligned
      U16 raw; raw.u = *reinterpret_cast<const uint4*>(S2g + (size_t)rt*32768 + r*256 + sc0);
      int tc0 = sc0 ^ swz;                     // true col (8-block preserved)
#pragma unroll
      for (int j = 0; j < 8; j++)
        sT[(tc0 + j)*136 + r] = raw.s[j];
    }
    __syncthreads();
#pragma unroll
    for (int ks = 0; ks < 4; ks++){
      const int k0 = ks*32 + lg*8;
      bf16x8 aA[2];
#pragma unroll
      for (int ii = 0; ii < 2; ii++)
        aA[ii] = *reinterpret_cast<const bf16x8*>(&sT[((2*wv+ii)*16 + lr)*136 + k0]);
#pragma unroll
      for (int j = 0; j < 16; j++){
        bf16x8 bB = *reinterpret_cast<const bf16x8*>(&sT[(j*16 + lr)*136 + k0]);
        gacc[0*16+j] = __builtin_amdgcn_mfma_f32_16x16x32_bf16(aA[0], bB, gacc[0*16+j], 0,0,0);
        gacc[1*16+j] = __builtin_amdgcn_mfma_f32_16x16x32_bf16(aA[1], bB, gacc[1*16+j], 0,0,0);
      }
    }
  }
  float* Gp = Gpart + (size_t)blk * 65536;
#pragma unroll
  for (int ii = 0; ii < 2; ii++)
#pragma unroll
    for (int j = 0; j < 16; j++)
#pragma unroll
      for (int i = 0; i < 4; i++){
        int ci = (2*wv + ii)*16 + lg*4 + i;
        int cj = j*16 + lr;
        Gp[ci*256 + cj] = gacc[ii*16+j][i];
      }
}

// ---------------- gred: reduce Gpart -> G (r5-verified) ----------------
__global__ __launch_bounds__(256) void gred_kernel(const float* __restrict__ Gpart,
                                                   float* __restrict__ G, int nPart){
  int i = blockIdx.x * 256 + threadIdx.x;
  float s = 0.f;
  for (int b = 0; b < nPart; b++) s += Gpart[(size_t)b * 65536 + i];
  G[i] = s;
}

// ---------------- ured: per-channel sums of U, U^2, colsum fgsum (r5-verified) --------------
__global__ __launch_bounds__(256) void ured_kernel(const float* __restrict__ U,
                                                   const float* __restrict__ fgsum,
                                                   float* __restrict__ Upart,
                                                   float* __restrict__ Usqpart,
                                                   float* __restrict__ CSpart){
  const int blk = blockIdx.x;
  const int slice = blk >> 3, part = blk & 7;
  const int t = threadIdx.x;
  {
    const int cl = t & 63, gsub = t >> 6;
    const int c = part*64 + cl;
    float su = 0.f, sq = 0.f;
    for (int g = slice*1024 + gsub; g < slice*1024 + 1024; g += 4){
      float u = U[(size_t)g * 512 + c];
      su += u; sq += u*u;
    }
    __shared__ float rU[4][64], rQ[4][64];
    rU[gsub][cl] = su; rQ[gsub][cl] = sq;
    __syncthreads();
    if (t < 64){
      Upart  [(size_t)slice*512 + part*64 + t] = rU[0][t]+rU[1][t]+rU[2][t]+rU[3][t];
      Usqpart[(size_t)slice*512 + part*64 + t] = rQ[0][t]+rQ[1][t]+rQ[2][t]+rQ[3][t];
    }
  }
  __syncthreads();
  {
    const int cl = t & 31, gsub = t >> 5;
    const int c2 = part*32 + cl;
    float cs = 0.f;
    for (int g = slice*1024 + gsub; g < slice*1024 + 1024; g += 8)
      cs += fgsum[(size_t)g * 256 + c2];
    __shared__ float rC[8][32];
    rC[gsub][cl] = cs;
    __syncthreads();
    if (t < 32){
      float s = 0.f;
#pragma unroll
      for (int k = 0; k < 8; k++) s += rC[k][t];
      CSpart[(size_t)slice*256 + part*32 + t] = s;
    }
  }
}

// ---------------- fin2: assemble BN2 scale/shift from moments (r5-verified) ----------------
__global__ __launch_bounds__(256) void fin2_kernel(const float* __restrict__ G,
                                                   const float* __restrict__ CSpart,
                                                   const float* __restrict__ Upart,
                                                   const float* __restrict__ Usqpart,
                                                   const float* __restrict__ UVpart,
                                                   const ushortT* __restrict__ W3bf,
                                                   const float* __restrict__ g2,
                                                   const float* __restrict__ be2,
                                                   float* __restrict__ scale2,
                                                   float* __restrict__ shift2){
  const int blk = blockIdx.x, t = threadIdx.x;
  __shared__ float sw[256];
  __shared__ float r1[4], r2[4], r3[4];
  float csf = 0.f;
#pragma unroll
  for (int s = 0; s < 8; s++) csf += CSpart[s*256 + t];
  for (int sub = 0; sub < 4; sub++){
    const int c = blk*4 + sub;
    sw[t] = bf2f(W3bf[(size_t)c*512 + 256 + t]);
    __syncthreads();
    const float wj = sw[t];
    float dot = 0.f;
    const float* Grow = G + (size_t)t * 256;
    for (int k = 0; k < 256; k++) dot += sw[k] * Grow[k];
    float quad = wj * dot;
    float cdot = wj * csf;
    float uvv  = (t < 128) ? UVpart[(size_t)t * 512 + c] : 0.f;
    float a = quad, bq = cdot, cq = uvv;
#pragma unroll
    for (int m = 32; m >= 1; m >>= 1){
      a  += __shfl_xor(a, m); bq += __shfl_xor(bq, m); cq += __shfl_xor(cq, m);
    }
    if ((t & 63) == 0){ r1[t>>6] = a; r2[t>>6] = bq; r3[t>>6] = cq; }
    __syncthreads();
    if (t == 0){
      float wGw  = r1[0]+r1[1]+r1[2]+r1[3];
      float csw  = r2[0]+r2[1]+r2[2]+r2[3];
      float sUV  = r3[0]+r3[1]+r3[2]+r3[3];
      float sU = 0.f, sQ = 0.f;
#pragma unroll
      for (int s = 0; s < 8; s++){
        sU += Upart  [s*512 + c];
        sQ += Usqpart[s*512 + c];
      }
      const float invN = 1.0f / (float)R_;
      float mu = (csw + 32.f * sU) * invN;
      float e2 = (wGw + 2.f * sUV + 32.f * sQ) * invN;
      float var = e2 - mu * mu;
      float sc = rsqrtf(var + 1e-5f) * g2[c];
      scale2[c] = sc;
      shift2[c] = be2[c] - mu * sc;
    }
    __syncthreads();
  }
}

// ====== shared phase A: compute S2 tile (128 rows x 256 cols) into swizzled LDS ======
static __device__ __forceinline__ void phaseA_s2(const float* __restrict__ xyz,
                                                 const int* __restrict__ knnIdx,
                                                 const float4* __restrict__ F1c,
                                                 const ushortT* __restrict__ W2bf,
                                                 const float* __restrict__ b2,
                                                 ushortT* sS2, int blk,
                                                 int wv, int lr, int lg){
  bf16x8 a1[4];
  a1_frags(xyz, knnIdx, F1c, blk*128 + wv*16 + lr, lg, a1);
  f32x4 acc[16];
#pragma unroll
  for (int c = 0; c < 16; c++) acc[c] = (f32x4){0.f,0.f,0.f,0.f};
#pragma unroll
  for (int s = 0; s < 4; s++)
#pragma unroll
    for (int ct = 0; ct < 16; ct++){
      bf16x8 bb = *reinterpret_cast<const bf16x8*>(W2bf + (size_t)(ct*16+lr)*128 + s*32 + lg*8);
      acc[ct] = __builtin_amdgcn_mfma_f32_16x16x32_bf16(a1[s], bb, acc[ct], 0, 0, 0);
    }
#pragma unroll
  for (int ct = 0; ct < 16; ct++){
    int col = ct*16 + lr;
    float bb = b2[col];
#pragma unroll
    for (int i = 0; i < 4; i++){
      int row = wv*16 + lg*4 + i;
      sS2[row*256 + (col ^ ((row & 7) << 3))] = f2bf(acc[ct][i] + bb);
    }
  }
}

#define PHASE2(PASS, ACC)                                                               \
  {                                                                                     \
    _Pragma("unroll")                                                                   \
    for (int s = 0; s < 8; s++){                                                        \
      const int kk = s*32 + lg*8;                                                       \
      bf16x8 b0 = *reinterpret_cast<const bf16x8*>(                                     \
          W3bf + (size_t)((PASS)*256 + wv*32 + 0 + lr)*512 + 256 + kk);                 \
      bf16x8 b1 = *reinterpret_cast<const bf16x8*>(                                     \
          W3bf + (size_t)((PASS)*256 + wv*32 + 16 + lr)*512 + 256 + kk);                \
      _Pragma("unroll")                                                                 \
      for (int rf = 0; rf < 8; rf++){                                                   \
        int row = rf*16 + lr;                                                           \
        bf16x8 a = *reinterpret_cast<const bf16x8*>(                                    \
            &sS2[row*256 + (kk ^ ((row & 7) << 3))]);                                   \
        ACC[rf][0] = __builtin_amdgcn_mfma_f32_16x16x32_bf16(a, b0, ACC[rf][0], 0,0,0); \
        ACC[rf][1] = __builtin_amdgcn_mfma_f32_16x16x32_bf16(a, b1, ACC[rf][1], 0,0,0); \
      }                                                                                 \
    }                                                                                   \
  }

// ---------------- enc3 (FALLBACK): S2 -> S3 (+U) -> BN2 channel partials ----------------
__global__ __launch_bounds__(512) void enc3_kernel(const float* __restrict__ xyz,
                                                   const int* __restrict__ knnIdx,
                                                   const float4* __restrict__ F1c,
                                                   const ushortT* __restrict__ W2bf,
                                                   const float* __restrict__ b2,
                                                   const ushortT* __restrict__ W3bf,
                                                   const float* __restrict__ U,
                                                   float* __restrict__ P2sum,
                                                   float* __restrict__ P2sq){
  __shared__ ushortT sS2[128 * 256];
  const int blk = blockIdx.x;
  const int t = threadIdx.x, lane = t & 63, wv = t >> 6;
  const int lr = lane & 15, lg = lane >> 4;
  phaseA_s2(xyz, knnIdx, F1c, W2bf, b2, sS2, blk, wv, lr, lg);
  __syncthreads();
#pragma unroll
  for (int pass = 0; pass < 2; pass++){
    f32x4 acc[8][2];
#pragma unroll
    for (int rf = 0; rf < 8; rf++){ acc[rf][0] = (f32x4){0,0,0,0}; acc[rf][1] = (f32x4){0,0,0,0}; }
    PHASE2(pass, acc)
#pragma unroll
    for (int ct = 0; ct < 2; ct++){
      int col = pass*256 + wv*32 + ct*16 + lr;
      float s = 0.f, q = 0.f;
#pragma unroll
      for (int rf = 0; rf < 8; rf++){
        float uv = U[(size_t)(blk*4 + (rf >> 1)) * 512 + col];
#pragma unroll
        for (int i = 0; i < 4; i++){
          float v = acc[rf][ct][i] + uv;
          s += v; q += v * v;
        }
      }
      s += __shfl_xor(s, 16); s += __shfl_xor(s, 32);
      q += __shfl_xor(q, 16); q += __shfl_xor(q, 32);
      if (lg == 0){
        P2sum[(size_t)blk * 512 + col] = s;
        P2sq [(size_t)blk * 512 + col] = q;
      }
    }
  }
}

__global__ __launch_bounds__(256) void fin_kernel(const float* __restrict__ Psum,
                                                  const float* __restrict__ Psq,
                                                  int nPart, int C, float invN,
                                                  const float* __restrict__ g,
                                                  const float* __restrict__ be,
                                                  float* __restrict__ scale,
                                                  float* __restrict__ shift){
  const int ch = blockIdx.x, t = threadIdx.x;
  float s = 0.f, q = 0.f;
  for (int i = t; i < nPart; i += 256){
    s += Psum[(size_t)i * C + ch];
    q += Psq [(size_t)i * C + ch];
  }
  __shared__ float ls[4], lq[4];
#pragma unroll
  for (int m = 32; m >= 1; m >>= 1){ s += __shfl_xor(s, m); q += __shfl_xor(q, m); }
  if ((t & 63) == 0){ ls[t >> 6] = s; lq[t >> 6] = q; }
  __syncthreads();
  if (t == 0){
    s = ls[0] + ls[1] + ls[2] + ls[3];
    q = lq[0] + lq[1] + lq[2] + lq[3];
    float mu = s * invN;
    float var = q * invN - mu * mu;
    float sc = rsqrtf(var + 1e-5f) * g[ch];
    scale[ch] = sc;
    shift[ch] = be[ch] - mu * sc;
  }
}

// ====== enc4 epilogue shared by both variants (S2 already in sS2) ======
#define ENC4_BODY                                                                       \
  f32x4 acc0[8][2], acc1[8][2];                                                         \
  _Pragma("unroll")                                                                     \
  for (int rf = 0; rf < 8; rf++){                                                       \
    acc0[rf][0] = (f32x4){0,0,0,0}; acc0[rf][1] = (f32x4){0,0,0,0};                     \
    acc1[rf][0] = (f32x4){0,0,0,0}; acc1[rf][1] = (f32x4){0,0,0,0};                     \
  }                                                                                     \
  PHASE2(0, acc0)                                                                       \
  PHASE2(1, acc1)                                                                       \
  __syncthreads();                                                                      \
  f32x4 accF[8];                                                                        \
  _Pragma("unroll")                                                                     \
  for (int rf = 0; rf < 8; rf++) accF[rf] = (f32x4){0,0,0,0};                           \
  _Pragma("unroll")                                                                     \
  for (int ct = 0; ct < 2; ct++){                                                       \
    int colh = wv*32 + ct*16 + lr;                                                      \
    _Pragma("unroll")                                                                   \
    for (int rf = 0; rf < 8; rf++){                                                     \
      float uv = U[(size_t)(blk*4 + (rf >> 1)) * 512 + colh];                           \
      _Pragma("unroll")                                                                 \
      for (int i = 0; i < 4; i++){                                                      \
        int row = rf*16 + lg*4 + i;                                                     \
        float v = acc0[rf][ct][i] + uv;                                                 \
        sS2[row*256 + (colh ^ ((row & 7) << 3))] =                                      \
            f2bf(fmaxf(fmaf(v, s_sc[colh], s_sh[colh]), 0.f));                          \
      }                                                                                 \
    }                                                                                   \
  }                                                                                     \
  __syncthreads();                                                                      \
  _Pragma("unroll")                                                                     \
  for (int s = 0; s < 8; s++){                                                          \
    const int kk = s*32 + lg*8;                                                         \
    bf16x8 b = *reinterpret_cast<const bf16x8*>(W4bf + (size_t)(wv*16 + lr)*512 + kk);  \
    _Pragma("unroll")                                                                   \
    for (int rf = 0; rf < 8; rf++){                                                     \
      int row = rf*16 + lr;                                                             \
      bf16x8 a = *reinterpret_cast<const bf16x8*>(&sS2[row*256 + (kk ^ ((row & 7) << 3))]); \
      accF[rf] = __builtin_amdgcn_mfma_f32_16x16x32_bf16(a, b, accF[rf], 0, 0, 0);      \
    }                                                                                   \
  }                                                                                     \
  __syncthreads();                                                                      \
  _Pragma("unroll")                                                                     \
  for (int ct = 0; ct < 2; ct++){                                                       \
    int colh = wv*32 + ct*16 + lr;                                                      \
    int col  = 256 + colh;                                                              \
    _Pragma("unroll")                                                                   \
    for (int rf = 0; rf < 8; rf++){                                                     \
      float uv = U[(size_t)(blk*4 + (rf >> 1)) * 512 + col];                            \
      _Pragma("unroll")                                                                 \
      for (int i = 0; i < 4; i++){                                                      \
        int row = rf*16 + lg*4 + i;                                                     \
        float v = acc1[rf][ct][i] + uv;                                                 \
        sS2[row*256 + (colh ^ ((row & 7) << 3))] =                                      \
            f2bf(fmaxf(fmaf(v, s_sc[col], s_sh[col]), 0.f));                            \
      }                                                                                 \
    }                                                                                   \
  }                                                                                     \
  __syncthreads();                                                                      \
  _Pragma("unroll")                                                                     \
  for (int s = 0; s < 8; s++){                                                          \
    const int kk = s*32 + lg*8;                                                         \
    bf16x8 b = *reinterpret_cast<const bf16x8*>(W4bf + (size_t)(wv*16 + lr)*512 + 256 + kk); \
    _Pragma("unroll")                                                                   \
    for (int rf = 0; rf < 8; rf++){                                                     \
      int row = rf*16 + lr;                                                             \
      bf16x8 a = *reinterpret_cast<const bf16x8*>(&sS2[row*256 + (kk ^ ((row & 7) << 3))]); \
      accF[rf] = __builtin_amdgcn_mfma_f32_16x16x32_bf16(a, b, accF[rf], 0, 0, 0);      \
    }                                                                                   \
  }                                                                                     \
  const float bb4 = b4[wv*16 + lr];                                                     \
  _Pragma("unroll")                                                                     \
  for (int gl = 0; gl < 4; gl++){                                                       \
    float m = -3.0e38f;                                                                 \
    _Pragma("unroll")                                                                   \
    for (int i = 0; i < 4; i++){                                                        \
      m = fmaxf(m, accF[2*gl    ][i]);                                                  \
      m = fmaxf(m, accF[2*gl + 1][i]);                                                  \
    }                                                                                   \
    m = fmaxf(m, __shfl_xor(m, 16));                                                    \
    m = fmaxf(m, __shfl_xor(m, 32));                                                    \
    if (lg == 0)                                                                        \
      feat[((size_t)blk*4 + gl)*128 + wv*16 + lr] = m + bb4;                            \
  }

// ---------------- enc4 (FALLBACK): recompute S2, then epilogue ----------------
__global__ __launch_bounds__(512) void enc4_kernel(const float* __restrict__ xyz,
                                                   const int* __restrict__ knnIdx,
                                                   const float4* __restrict__ F1c,
                                                   const ushortT* __restrict__ W2bf,
                                                   const float* __restrict__ b2,
                                                   const ushortT* __restrict__ W3bf,
                                                   const float* __restrict__ U,
                                                   const float* __restrict__ scale2,
                                                   const float* __restrict__ shift2,
                                                   const ushortT* __restrict__ W4bf,
                                                   const float* __restrict__ b4,
                                                   float* __restrict__ feat){
  __shared__ ushortT sS2[128 * 256];
  __shared__ float s_sc[512], s_sh[512];
  const int blk = blockIdx.x;
  const int t = threadIdx.x, lane = t & 63, wv = t >> 6;
  const int lr = lane & 15, lg = lane >> 4;
  if (t < 512){ s_sc[t] = scale2[t]; s_sh[t] = shift2[t]; }
  phaseA_s2(xyz, knnIdx, F1c, W2bf, b2, sS2, blk, wv, lr, lg);
  __syncthreads();
  ENC4_BODY
}

// ---------------- enc4r (S2 PATH): load S2 tile from global, then epilogue ----------------
__global__ __launch_bounds__(512) void enc4r_kernel(const ushortT* __restrict__ S2g,
                                                    const ushortT* __restrict__ W3bf,
                                                    const float* __restrict__ U,
                                                    const float* __restrict__ scale2,
                                                    const float* __restrict__ shift2,
                                                    const ushortT* __restrict__ W4bf,
                                                    const float* __restrict__ b4,
                                                    float* __restrict__ feat){
  __shared__ ushortT sS2[128 * 256];
  __shared__ float s_sc[512], s_sh[512];
  const int blk = blockIdx.x;
  const int t = threadIdx.x, lane = t & 63, wv = t >> 6;
  const int lr = lane & 15, lg = lane >> 4;
  if (t < 512){ s_sc[t] = scale2[t]; s_sh[t] = shift2[t]; }
  {
    const uint4* src = reinterpret_cast<const uint4*>(S2g + (size_t)blk * 32768);
    uint4* dst = reinterpret_cast<uint4*>(sS2);
#pragma unroll
    for (int i = 0; i < 8; i++) dst[t + i*512] = src[t + i*512];
  }
  __syncthreads();
  ENC4_BODY
}

extern "C" void kernel_launch(void* const* d_in, const int* in_sizes, int n_in,
                              void* d_out, int out_size, void* d_ws, size_t ws_size,
                              hipStream_t stream){
  const float* xyz = (const float*)d_in[0];
  const float* W1  = (const float*)d_in[1];
  const float* b1  = (const float*)d_in[2];
  const float* g1  = (const float*)d_in[3];
  const float* be1 = (const float*)d_in[4];
  const float* W2  = (const float*)d_in[5];
  const float* b2  = (const float*)d_in[6];
  const float* W3  = (const float*)d_in[7];
  const float* b3  = (const float*)d_in[8];
  const float* g2  = (const float*)d_in[9];
  const float* be2 = (const float*)d_in[10];
  const float* W4  = (const float*)d_in[11];
  const float* b4  = (const float*)d_in[12];

  float* out = (float*)d_out;
  float* center = out;                         // (16,512,3)
  float* feat   = out + (size_t)B_ * G_ * 3;   // (16,512,128)

  char* p = (char*)d_ws;
  size_t used = 0;
  auto alloc = [&](size_t bytes) -> char* {
    char* r = p + used; used += (bytes + 255) & ~(size_t)255; return r;
  };
  // ---- common allocations (~22 MB) ----
  int*     knnIdx = (int*)    alloc((size_t)R_ * 4);           // 1 MB
  ushortT* W2bf   = (ushortT*)alloc(32768 * 2);
  ushortT* W3bf   = (ushortT*)alloc(262144 * 2);
  ushortT* W4bf   = (ushortT*)alloc(65536 * 2);
  float4*  F1c    = (float4*) alloc(128 * 16);
  float*   Mpart  = (float*)  alloc(256 * 9 * 4);
  ushortT* fg     = (ushortT*)alloc((size_t)M_ * 256 * 2);     // 4 MB
  float*   U      = (float*)  alloc((size_t)M_ * 512 * 4);     // 16 MB
  float*   scale2 = (float*)  alloc(512 * 4);
  float*   shift2 = (float*)  alloc(512 * 4);

  // ---- S2-materialization gate (r8/r9: NBG>0 path ran and won) ----
  const size_t s2_b    = (size_t)R_ * 256 * 2;                 // 128 MB
  const size_t fgsum_b = (size_t)M_ * 256 * 4;                 // 8 MB
  const size_t small_b = (256*1024) + (256*1024) + (64*1024);  // UVpart + G + parts
  const size_t margin  = 4u << 20;
  int NBG = 0;
  if      (ws_size >= used + s2_b + fgsum_b + small_b + (size_t)256*65536*4 + margin) NBG = 256;
  else if (ws_size >= used + s2_b + fgsum_b + small_b + (size_t)128*65536*4 + margin) NBG = 128;
  else if (ws_size >= used + s2_b + fgsum_b + small_b + (size_t)64 *65536*4 + margin) NBG = 64;

  cast3_kernel  <<<dim3(1024), dim3(256),  0, stream>>>(W2, W3, W4, W2bf, W3bf, W4bf);
  fps_kernel    <<<dim3(B_),   dim3(512),  0, stream>>>(xyz, center);
  knn_kernel    <<<dim3(M_),   dim3(256),  0, stream>>>(xyz, center, knnIdx);
  moments_kernel<<<dim3(256),  dim3(256),  0, stream>>>(xyz, knnIdx, Mpart);
  prep1_kernel  <<<dim3(1),    dim3(128),  0, stream>>>(Mpart, W1, b1, g1, be1, F1c);

  if (NBG){
    float*   fgsum   = (float*)  alloc(fgsum_b);
    ushortT* S2g     = (ushortT*)alloc(s2_b);
    float*   UVpart  = (float*)  alloc(128 * 512 * 4);
    float*   G       = (float*)  alloc(65536 * 4);
    float*   Upart   = (float*)  alloc(8 * 512 * 4);
    float*   Usqpart = (float*)  alloc(8 * 512 * 4);
    float*   CSpart  = (float*)  alloc(8 * 256 * 4);
    float*   Gpart   = (float*)  alloc((size_t)NBG * 65536 * 4);
    enc2s_kernel<<<dim3(2048), dim3(512), 0, stream>>>(xyz, knnIdx, F1c, W2bf, b2, fg, fgsum, S2g);
    u_kernel    <<<dim3(512),  dim3(256), 0, stream>>>(fg, W3bf, b3, U);
    v_kernel    <<<dim3(512),  dim3(256), 0, stream>>>(fgsum, W3bf, U, UVpart);
    gram2_kernel<<<dim3(NBG),  dim3(512), 0, stream>>>(S2g, Gpart, 2048/NBG);
    gred_kernel <<<dim3(256),  dim3(256), 0, stream>>>(Gpart, G, NBG);
    ured_kernel <<<dim3(64),   dim3(256), 0, stream>>>(U, fgsum, Upart, Usqpart, CSpart);
    fin2_kernel <<<dim3(128),  dim3(256), 0, stream>>>(G, CSpart, Upart, Usqpart, UVpart,
                                                       W3bf, g2, be2, scale2, shift2);
    enc4r_kernel<<<dim3(2048), dim3(512), 0, stream>>>(S2g, W3bf, U, scale2, shift2, W4bf, b4, feat);
  } else {
    float* P2sum = (float*)alloc((size_t)2048 * 512 * 4);      // 4 MB
    float* P2sq  = (float*)alloc((size_t)2048 * 512 * 4);      // 4 MB
    f2g_kernel <<<dim3(4096), dim3(256), 0, stream>>>(xyz, knnIdx, F1c, W2bf, b2, fg);
    u_kernel   <<<dim3(512),  dim3(256), 0, stream>>>(fg, W3bf, b3, U);
    enc3_kernel<<<dim3(2048), dim3(512), 0, stream>>>(xyz, knnIdx, F1c, W2bf, b2, W3bf, U, P2sum, P2sq);
    fin_kernel <<<dim3(512),  dim3(256), 0, stream>>>(P2sum, P2sq, 2048, 512, 1.0f/(float)R_,
                                                      g2, be2, scale2, shift2);
    enc4_kernel<<<dim3(2048), dim3(512), 0, stream>>>(xyz, knnIdx, F1c, W2bf, b2, W3bf, U,
                                                      scale2, shift2, W4bf, b4, feat);
  }
}